// Round 2
// baseline (955.735 us; speedup 1.0000x reference)
//
#include <hip/hip_runtime.h>
#include <math.h>

// Problem constants
#define BQ 8
#define SEQ 577
#define CH 768
#define NH 12
#define HD 64
#define M_ROWS (BQ * SEQ)      // 4616
#define QKV_CH (3 * CH)        // 2304
#define EPSF 1.1920929e-07f
#define F2P31 2147483648.0f    // float32(2^31 - 1) rounds to 2^31 -- replicate jnp

#if defined(__has_builtin)
#  if __has_builtin(__builtin_amdgcn_sdot4)
#    define HAVE_SDOT4 1
#  endif
#endif

__device__ __forceinline__ int dot4(int a, int b, int c) {
#ifdef HAVE_SDOT4
  return __builtin_amdgcn_sdot4(a, b, c, false);
#else
  c += (int)(signed char)(a)       * (int)(signed char)(b);
  c += (int)(signed char)(a >> 8)  * (int)(signed char)(b >> 8);
  c += (int)(signed char)(a >> 16) * (int)(signed char)(b >> 16);
  c += (int)(signed char)(a >> 24) * (int)(signed char)(b >> 24);
  return c;
#endif
}

// ---------------- global abs-max of a float tensor (exact, order-independent) --------
__global__ void k_absmax(const float* __restrict__ x, int n, unsigned* __restrict__ gmax) {
  float m = 0.f;
  int stride = gridDim.x * blockDim.x;
  for (int i = blockIdx.x * blockDim.x + threadIdx.x; i < n; i += stride)
    m = fmaxf(m, fabsf(x[i]));
#pragma unroll
  for (int off = 32; off; off >>= 1) m = fmaxf(m, __shfl_xor(m, off, 64));
  __shared__ float red[4];
  if ((threadIdx.x & 63) == 0) red[threadIdx.x >> 6] = m;
  __syncthreads();
  if (threadIdx.x == 0) {
    float mm = red[0];
    for (int i = 1; i < (int)(blockDim.x >> 6); ++i) mm = fmaxf(mm, red[i]);
    atomicMax(gmax, __float_as_uint(mm));
  }
}

// ---------------- per-row weight quant: s = max(|row|)/127 clamp eps; w8 = clip(rint(w/s)) ----
__global__ void k_wquant(const float* __restrict__ w, int K,
                         signed char* __restrict__ w8, float* __restrict__ sw) {
  int row = blockIdx.x;
  const float* wr = w + (size_t)row * K;
  float m = 0.f;
  for (int c = threadIdx.x; c < K; c += blockDim.x) m = fmaxf(m, fabsf(wr[c]));
#pragma unroll
  for (int off = 32; off; off >>= 1) m = fmaxf(m, __shfl_xor(m, off, 64));
  __shared__ float red[4];
  if ((threadIdx.x & 63) == 0) red[threadIdx.x >> 6] = m;
  __syncthreads();
  float mm = fmaxf(fmaxf(red[0], red[1]), fmaxf(red[2], red[3]));
  float s = fmaxf(mm / 127.0f, EPSF);
  if (threadIdx.x == 0) sw[row] = s;
  for (int c = threadIdx.x; c < K; c += blockDim.x) {
    float q = rintf(wr[c] / s);
    q = fminf(fmaxf(q, -128.f), 127.f);
    w8[(size_t)row * K + c] = (signed char)q;
  }
}

// ---------------- per-tensor activation quant ----------------
__global__ void k_aquant(const float* __restrict__ x, int n,
                         const unsigned* __restrict__ hdr, signed char* __restrict__ x8) {
  float s = fmaxf(__uint_as_float(hdr[0]) / 127.0f, EPSF);
  int stride = gridDim.x * blockDim.x;
  for (int i = blockIdx.x * blockDim.x + threadIdx.x; i < n; i += stride) {
    float q = rintf(x[i] / s);
    q = fminf(fmaxf(q, -128.f), 127.f);
    x8[i] = (signed char)q;
  }
}

// ---------------- GEMM1: qkv_int = X8[M,K] * WQ8[N,K]^T + rint(bias/acc_s); track max|qkv_f| ----
__global__ __launch_bounds__(256) void k_gemm_qkv(
    const signed char* __restrict__ A, const signed char* __restrict__ Bm,
    const float* __restrict__ swq, const float* __restrict__ bias,
    const unsigned* __restrict__ hdr, int* __restrict__ Cq, unsigned* __restrict__ gq) {
  const int K = CH, Nc = QKV_CH, M = M_ROWS;
  __shared__ int As[64][9];
  __shared__ int Bs[64][9];
  __shared__ float red[4];
  int tx = threadIdx.x & 15;
  int ty = threadIdx.x >> 4;
  int row0 = blockIdx.y * 64;
  int col0 = blockIdx.x * 64;
  int acc[4][4] = {};
  for (int k0 = 0; k0 < K; k0 += 32) {
    for (int l = threadIdx.x; l < 512; l += 256) {
      int r = l >> 3, c = l & 7;
      int rg = row0 + r;
      As[r][c] = (rg < M) ? *(const int*)(A + (size_t)rg * K + k0 + (c << 2)) : 0;
      Bs[r][c] = *(const int*)(Bm + (size_t)(col0 + r) * K + k0 + (c << 2));
    }
    __syncthreads();
#pragma unroll
    for (int kk = 0; kk < 8; ++kk) {
      int a[4], b[4];
#pragma unroll
      for (int i = 0; i < 4; ++i) a[i] = As[ty * 4 + i][kk];
#pragma unroll
      for (int j = 0; j < 4; ++j) b[j] = Bs[tx * 4 + j][kk];
#pragma unroll
      for (int i = 0; i < 4; ++i)
#pragma unroll
        for (int j = 0; j < 4; ++j) acc[i][j] = dot4(a[i], b[j], acc[i][j]);
    }
    __syncthreads();
  }
  float s_x = fmaxf(__uint_as_float(hdr[0]) / 127.0f, EPSF);
  float lmax = 0.f;
  for (int i = 0; i < 4; ++i) {
    int r = row0 + ty * 4 + i;
    if (r >= M) continue;
    for (int j = 0; j < 4; ++j) {
      int c = col0 + tx * 4 + j;
      float accs = s_x * swq[c];
      int bint = (int)rintf(bias[c] / accs);
      int qv = acc[i][j] + bint;
      Cq[(size_t)r * Nc + c] = qv;
      lmax = fmaxf(lmax, fabsf((float)qv * accs));
    }
  }
#pragma unroll
  for (int off = 32; off; off >>= 1) lmax = fmaxf(lmax, __shfl_xor(lmax, off, 64));
  if ((threadIdx.x & 63) == 0) red[threadIdx.x >> 6] = lmax;
  __syncthreads();
  if (threadIdx.x == 0)
    atomicMax(gq, __float_as_uint(fmaxf(fmaxf(red[0], red[1]), fmaxf(red[2], red[3]))));
}

// ---------------- per-channel fixedpoint requant constants for qkv ----------------
__global__ void k_qkv_prep(const float* __restrict__ swq, const unsigned* __restrict__ hdr,
                           float* __restrict__ mq, float* __restrict__ pwq) {
  int o = blockIdx.x * blockDim.x + threadIdx.x;
  if (o >= QKV_CH) return;
  float s_x = fmaxf(__uint_as_float(hdr[0]) / 127.0f, EPSF);
  float s_qkv = fmaxf(__uint_as_float(hdr[1]) / 127.0f, EPSF);
  float ns = (s_x * swq[o]) / s_qkv;
  int e;
  float f = frexpf(ns, &e);             // ns = f * 2^e, f in [0.5,1) == floor(log2)+1
  mq[o] = floorf(f * F2P31 + 0.5f);     // ROUND_HALF_UP mantissa * 2^31
  pwq[o] = exp2f((float)e - 31.0f);
}

// ---------------- requant qkv -> int8 q/k/v in [B,H,N,D] layout ----------------
__global__ void k_qkv_requant(const int* __restrict__ Cq, const float* __restrict__ swq,
                              const float* __restrict__ mq, const float* __restrict__ pwq,
                              const unsigned* __restrict__ hdr,
                              signed char* __restrict__ Q8, signed char* __restrict__ K8,
                              signed char* __restrict__ V8) {
  float s_x = fmaxf(__uint_as_float(hdr[0]) / 127.0f, EPSF);
  int total = M_ROWS * QKV_CH;
  int stride = gridDim.x * blockDim.x;
  for (int i = blockIdx.x * blockDim.x + threadIdx.x; i < total; i += stride) {
    int o = i % QKV_CH;
    int bn = i / QKV_CH;
    float accs = s_x * swq[o];
    float qf = (float)Cq[i] * accs;           // fl(qkv_int * acc_s) as reference
    float z = rintf(qf / accs);               // replicate round(pa/pre_s)
    float t8 = rintf((z * mq[o]) * pwq[o]);   // round(z_int*m * 2^(e-31))
    t8 = fminf(fmaxf(t8, -128.f), 127.f);
    int s = o / CH;
    int rem = o - s * CH;
    int h = rem >> 6, d = rem & 63;
    int b = bn / SEQ, n = bn - b * SEQ;
    size_t dst = (((size_t)(b * NH + h) * SEQ + n) << 6) + d;
    signed char v = (signed char)t8;
    if (s == 0) Q8[dst] = v;
    else if (s == 1) K8[dst] = v;
    else V8[dst] = v;
  }
}

// ---------------- attention: one wave per (b,h,n) row ----------------
__global__ __launch_bounds__(64) void k_attn(
    const signed char* __restrict__ Q8, const signed char* __restrict__ K8,
    const signed char* __restrict__ V8, const unsigned* __restrict__ hdr,
    int* __restrict__ ctxi, unsigned* __restrict__ gctx) {
  int bid = blockIdx.x;
  int n = bid % SEQ;
  int bh = bid / SEQ;
  int b = bh / NH, h = bh - b * NH;
  int t = threadIdx.x;

  __shared__ int qrow[16];
  __shared__ int ibuf[SEQ];
  __shared__ float ebuf[SEQ];

  size_t rowbase = ((size_t)bh * SEQ + n) * 64;
  if (t < 16) qrow[t] = ((const int*)(Q8 + rowbase))[t];
  __syncthreads();

  size_t kb = (size_t)bh * SEQ * 64;
  int lmax = -2147483647;
  for (int m = t; m < SEQ; m += 64) {
    const int4* kr = (const int4*)(K8 + kb + ((size_t)m << 6));
    int acc = 0;
#pragma unroll
    for (int u = 0; u < 4; ++u) {
      int4 p = kr[u];
      acc = dot4(qrow[4 * u + 0], p.x, acc);
      acc = dot4(qrow[4 * u + 1], p.y, acc);
      acc = dot4(qrow[4 * u + 2], p.z, acc);
      acc = dot4(qrow[4 * u + 3], p.w, acc);
    }
    ibuf[m] = acc;
    lmax = max(lmax, acc);
  }
#pragma unroll
  for (int off = 32; off; off >>= 1) lmax = max(lmax, __shfl_xor(lmax, off, 64));

  float s_qkv = fmaxf(__uint_as_float(hdr[1]) / 127.0f, EPSF);
  float s_attn = (s_qkv * s_qkv) * 0.125f;    // D^-0.5 = 0.125 exact
  float x0 = floorf(-1.0f / s_attn);
  float nx0 = 15.0f * x0;
  double dsum = 0.0;
  for (int m = t; m < SEQ; m += 64) {
    float xi = (float)(ibuf[m] - lmax);
    xi = xi + floorf(xi * 0.5f) - floorf(xi * 0.0625f);  // /2, /16 exact pow2
    xi = fmaxf(xi, nx0);
    float qd = floorf(xi / x0);
    float r = xi - x0 * qd;
    float ei = floorf((r * 0.5f - x0) * exp2f(15.0f - qd));
    ei = fmaxf(ei, 0.0f);
    ebuf[m] = ei;
    dsum += (double)ei;   // exact (each ei exact; clamp margin huge so order-safe)
  }
#pragma unroll
  for (int off = 32; off; off >>= 1) dsum += __shfl_xor(dsum, off, 64);
  float esum = fminf((float)dsum, F2P31);
  float factor = floorf(F2P31 / esum);
  for (int m = t; m < SEQ; m += 64)
    ibuf[m] = (int)floorf((ebuf[m] * factor) * 5.9604644775390625e-08f);  // /2^24 exact
  __syncthreads();

  const signed char* vb = V8 + kb;
  int cacc = 0;
  for (int m = 0; m < SEQ; ++m) cacc += ibuf[m] * (int)vb[((size_t)m << 6) + t];
  size_t ci = ((size_t)(b * SEQ + n)) * CH + (size_t)h * 64 + t;
  ctxi[ci] = cacc;
  float pre_s = 0.0078125f * s_qkv;  // s_sm * s_qkv (exact pow2 scale)
  float av = fabsf((float)cacc * pre_s);
#pragma unroll
  for (int off = 32; off; off >>= 1) av = fmaxf(av, __shfl_xor(av, off, 64));
  if (t == 0) atomicMax(gctx, __float_as_uint(av));
}

// ---------------- requant ctx -> int8 ----------------
__global__ void k_ctx_requant(const int* __restrict__ ctxi, const unsigned* __restrict__ hdr,
                              signed char* __restrict__ C8) {
  float s_qkv = fmaxf(__uint_as_float(hdr[1]) / 127.0f, EPSF);
  float pre_s = 0.0078125f * s_qkv;
  float s_ctx = fmaxf(__uint_as_float(hdr[2]) / 127.0f, EPSF);
  float ns = pre_s / s_ctx;
  int e;
  float f = frexpf(ns, &e);
  float mm = floorf(f * F2P31 + 0.5f);
  float pw = exp2f((float)e - 31.0f);
  int total = M_ROWS * CH;
  int stride = gridDim.x * blockDim.x;
  for (int i = blockIdx.x * blockDim.x + threadIdx.x; i < total; i += stride) {
    float cf = (float)ctxi[i] * pre_s;
    float z = rintf(cf / pre_s);
    float t8 = rintf((z * mm) * pw);
    t8 = fminf(fmaxf(t8, -128.f), 127.f);
    C8[i] = (signed char)t8;
  }
}

// ---------------- GEMM2: out = (C8[M,K]*WP8[N,K]^T + rint(b/out_s)) * out_s ----------------
__global__ __launch_bounds__(256) void k_gemm_out(
    const signed char* __restrict__ A, const signed char* __restrict__ Bm,
    const float* __restrict__ swp, const float* __restrict__ bias,
    const unsigned* __restrict__ hdr, float* __restrict__ outp) {
  const int K = CH, Nc = CH, M = M_ROWS;
  __shared__ int As[64][9];
  __shared__ int Bs[64][9];
  int tx = threadIdx.x & 15;
  int ty = threadIdx.x >> 4;
  int row0 = blockIdx.y * 64;
  int col0 = blockIdx.x * 64;
  int acc[4][4] = {};
  for (int k0 = 0; k0 < K; k0 += 32) {
    for (int l = threadIdx.x; l < 512; l += 256) {
      int r = l >> 3, c = l & 7;
      int rg = row0 + r;
      As[r][c] = (rg < M) ? *(const int*)(A + (size_t)rg * K + k0 + (c << 2)) : 0;
      Bs[r][c] = *(const int*)(Bm + (size_t)(col0 + r) * K + k0 + (c << 2));
    }
    __syncthreads();
#pragma unroll
    for (int kk = 0; kk < 8; ++kk) {
      int a[4], b[4];
#pragma unroll
      for (int i = 0; i < 4; ++i) a[i] = As[ty * 4 + i][kk];
#pragma unroll
      for (int j = 0; j < 4; ++j) b[j] = Bs[tx * 4 + j][kk];
#pragma unroll
      for (int i = 0; i < 4; ++i)
#pragma unroll
        for (int j = 0; j < 4; ++j) acc[i][j] = dot4(a[i], b[j], acc[i][j]);
    }
    __syncthreads();
  }
  float s_ctx = fmaxf(__uint_as_float(hdr[2]) / 127.0f, EPSF);
  for (int i = 0; i < 4; ++i) {
    int r = row0 + ty * 4 + i;
    if (r >= M) continue;
    for (int j = 0; j < 4; ++j) {
      int c = col0 + tx * 4 + j;
      float outs = s_ctx * swp[c];
      int bint = (int)rintf(bias[c] / outs);
      outp[(size_t)r * Nc + c] = (float)(acc[i][j] + bint) * outs;
    }
  }
}

extern "C" void kernel_launch(void* const* d_in, const int* in_sizes, int n_in,
                              void* d_out, int out_size, void* d_ws, size_t ws_size,
                              hipStream_t stream) {
  const float* x = (const float*)d_in[0];
  const float* w_qkv = (const float*)d_in[1];
  const float* b_qkv = (const float*)d_in[2];
  const float* w_proj = (const float*)d_in[3];
  const float* b_proj = (const float*)d_in[4];
  float* outp = (float*)d_out;

  // ---- workspace layout: bump allocator, 4 KB aligned (fixes R1 overlap bug) ----
  char* ws = (char*)d_ws;
  size_t off = 0;
  auto alloc = [&](size_t sz) -> char* {
    char* p = ws + off;
    off = (off + sz + 4095) & ~(size_t)4095;
    return p;
  };
  unsigned* hdr = (unsigned*)alloc(256);               // [0]=max|x| [1]=max|qkv_f| [2]=max|ctx_f|
  float* SWQ = (float*)alloc(QKV_CH * 4);
  float* SWP = (float*)alloc(CH * 4);
  float* MQ  = (float*)alloc(QKV_CH * 4);
  float* PWQ = (float*)alloc(QKV_CH * 4);
  signed char* WQ8 = (signed char*)alloc((size_t)QKV_CH * CH);
  signed char* WP8 = (signed char*)alloc((size_t)CH * CH);
  signed char* X8  = (signed char*)alloc((size_t)M_ROWS * CH);
  signed char* Q8  = (signed char*)alloc((size_t)M_ROWS * CH);
  signed char* K8  = (signed char*)alloc((size_t)M_ROWS * CH);
  signed char* V8  = (signed char*)alloc((size_t)M_ROWS * CH);
  signed char* C8  = (signed char*)alloc((size_t)M_ROWS * CH);
  int* QKVI = (int*)alloc((size_t)M_ROWS * QKV_CH * 4);
  int* CTXI = (int*)alloc((size_t)M_ROWS * CH * 4);
  (void)ws_size;

  hipMemsetAsync(hdr, 0, 256, stream);
  int nx = BQ * SEQ * CH;
  k_absmax<<<1024, 256, 0, stream>>>(x, nx, hdr + 0);
  k_wquant<<<QKV_CH, 256, 0, stream>>>(w_qkv, CH, WQ8, SWQ);
  k_wquant<<<CH, 256, 0, stream>>>(w_proj, CH, WP8, SWP);
  k_aquant<<<2048, 256, 0, stream>>>(x, nx, hdr, X8);
  dim3 g1(QKV_CH / 64, (M_ROWS + 63) / 64);
  k_gemm_qkv<<<g1, 256, 0, stream>>>(X8, WQ8, SWQ, b_qkv, hdr, QKVI, hdr + 1);
  k_qkv_prep<<<(QKV_CH + 255) / 256, 256, 0, stream>>>(SWQ, hdr, MQ, PWQ);
  k_qkv_requant<<<2048, 256, 0, stream>>>(QKVI, SWQ, MQ, PWQ, hdr, Q8, K8, V8);
  k_attn<<<BQ * NH * SEQ, 64, 0, stream>>>(Q8, K8, V8, hdr, CTXI, hdr + 2);
  k_ctx_requant<<<2048, 256, 0, stream>>>(CTXI, hdr, C8);
  dim3 g2(CH / 64, (M_ROWS + 63) / 64);
  k_gemm_out<<<g2, 256, 0, stream>>>(C8, WP8, SWP, b_proj, hdr, outp);
}

// Round 3
// 483.168 us; speedup vs baseline: 1.9781x; 1.9781x over previous
//
#include <hip/hip_runtime.h>
#include <math.h>

// Problem constants
#define BQ 8
#define SEQ 577
#define CH 768
#define NH 12
#define HD 64
#define M_ROWS (BQ * SEQ)      // 4616
#define QKV_CH (3 * CH)        // 2304
#define EPSF 1.1920929e-07f
#define F2P31 2147483648.0f    // float32(2^31 - 1) rounds to 2^31 -- replicate jnp

#define KS_STRIDE 17           // K LDS row stride in ints (64B row + 4B pad)
#define VT_ROW 580             // Vt row bytes (577 padded to /4)
#define VT_WORDS 145

#if defined(__has_builtin)
#  if __has_builtin(__builtin_amdgcn_sdot4)
#    define HAVE_SDOT4 1
#  endif
#endif

__device__ __forceinline__ int dot4(int a, int b, int c) {
#ifdef HAVE_SDOT4
  return __builtin_amdgcn_sdot4(a, b, c, false);
#else
  c += (int)(signed char)(a)       * (int)(signed char)(b);
  c += (int)(signed char)(a >> 8)  * (int)(signed char)(b >> 8);
  c += (int)(signed char)(a >> 16) * (int)(signed char)(b >> 16);
  c += (int)(signed char)(a >> 24) * (int)(signed char)(b >> 24);
  return c;
#endif
}

// ---------------- global abs-max of a float tensor (exact, order-independent) --------
__global__ void k_absmax(const float* __restrict__ x, int n, unsigned* __restrict__ gmax) {
  float m = 0.f;
  int stride = gridDim.x * blockDim.x;
  for (int i = blockIdx.x * blockDim.x + threadIdx.x; i < n; i += stride)
    m = fmaxf(m, fabsf(x[i]));
#pragma unroll
  for (int off = 32; off; off >>= 1) m = fmaxf(m, __shfl_xor(m, off, 64));
  __shared__ float red[4];
  if ((threadIdx.x & 63) == 0) red[threadIdx.x >> 6] = m;
  __syncthreads();
  if (threadIdx.x == 0) {
    float mm = red[0];
    for (int i = 1; i < (int)(blockDim.x >> 6); ++i) mm = fmaxf(mm, red[i]);
    atomicMax(gmax, __float_as_uint(mm));
  }
}

// ---------------- per-row weight quant ----------------
__global__ void k_wquant(const float* __restrict__ w, int K,
                         signed char* __restrict__ w8, float* __restrict__ sw) {
  int row = blockIdx.x;
  const float* wr = w + (size_t)row * K;
  float m = 0.f;
  for (int c = threadIdx.x; c < K; c += blockDim.x) m = fmaxf(m, fabsf(wr[c]));
#pragma unroll
  for (int off = 32; off; off >>= 1) m = fmaxf(m, __shfl_xor(m, off, 64));
  __shared__ float red[4];
  if ((threadIdx.x & 63) == 0) red[threadIdx.x >> 6] = m;
  __syncthreads();
  float mm = fmaxf(fmaxf(red[0], red[1]), fmaxf(red[2], red[3]));
  float s = fmaxf(mm / 127.0f, EPSF);
  if (threadIdx.x == 0) sw[row] = s;
  for (int c = threadIdx.x; c < K; c += blockDim.x) {
    float q = rintf(wr[c] / s);
    q = fminf(fmaxf(q, -128.f), 127.f);
    w8[(size_t)row * K + c] = (signed char)q;
  }
}

// ---------------- per-tensor activation quant ----------------
__global__ void k_aquant(const float* __restrict__ x, int n,
                         const unsigned* __restrict__ hdr, signed char* __restrict__ x8) {
  float s = fmaxf(__uint_as_float(hdr[0]) / 127.0f, EPSF);
  int stride = gridDim.x * blockDim.x;
  for (int i = blockIdx.x * blockDim.x + threadIdx.x; i < n; i += stride) {
    float q = rintf(x[i] / s);
    q = fminf(fmaxf(q, -128.f), 127.f);
    x8[i] = (signed char)q;
  }
}

// ---------------- GEMM1: qkv_int = X8[M,K] * WQ8[N,K]^T + rint(bias/acc_s); track max|qkv_f| ----
__global__ __launch_bounds__(256) void k_gemm_qkv(
    const signed char* __restrict__ A, const signed char* __restrict__ Bm,
    const float* __restrict__ swq, const float* __restrict__ bias,
    const unsigned* __restrict__ hdr, int* __restrict__ Cq, unsigned* __restrict__ gq) {
  const int K = CH, Nc = QKV_CH, M = M_ROWS;
  __shared__ int As[64][9];
  __shared__ int Bs[64][9];
  __shared__ float red[4];
  int tx = threadIdx.x & 15;
  int ty = threadIdx.x >> 4;
  int row0 = blockIdx.y * 64;
  int col0 = blockIdx.x * 64;
  int acc[4][4] = {};
  for (int k0 = 0; k0 < K; k0 += 32) {
    for (int l = threadIdx.x; l < 512; l += 256) {
      int r = l >> 3, c = l & 7;
      int rg = row0 + r;
      As[r][c] = (rg < M) ? *(const int*)(A + (size_t)rg * K + k0 + (c << 2)) : 0;
      Bs[r][c] = *(const int*)(Bm + (size_t)(col0 + r) * K + k0 + (c << 2));
    }
    __syncthreads();
#pragma unroll
    for (int kk = 0; kk < 8; ++kk) {
      int a[4], b[4];
#pragma unroll
      for (int i = 0; i < 4; ++i) a[i] = As[ty * 4 + i][kk];
#pragma unroll
      for (int j = 0; j < 4; ++j) b[j] = Bs[tx * 4 + j][kk];
#pragma unroll
      for (int i = 0; i < 4; ++i)
#pragma unroll
        for (int j = 0; j < 4; ++j) acc[i][j] = dot4(a[i], b[j], acc[i][j]);
    }
    __syncthreads();
  }
  float s_x = fmaxf(__uint_as_float(hdr[0]) / 127.0f, EPSF);
  float lmax = 0.f;
  for (int i = 0; i < 4; ++i) {
    int r = row0 + ty * 4 + i;
    if (r >= M) continue;
    for (int j = 0; j < 4; ++j) {
      int c = col0 + tx * 4 + j;
      float accs = s_x * swq[c];
      int bint = (int)rintf(bias[c] / accs);
      int qv = acc[i][j] + bint;
      Cq[(size_t)r * Nc + c] = qv;
      lmax = fmaxf(lmax, fabsf((float)qv * accs));
    }
  }
#pragma unroll
  for (int off = 32; off; off >>= 1) lmax = fmaxf(lmax, __shfl_xor(lmax, off, 64));
  if ((threadIdx.x & 63) == 0) red[threadIdx.x >> 6] = lmax;
  __syncthreads();
  if (threadIdx.x == 0)
    atomicMax(gq, __float_as_uint(fmaxf(fmaxf(red[0], red[1]), fmaxf(red[2], red[3]))));
}

// ---------------- per-channel fixedpoint requant constants for qkv ----------------
__global__ void k_qkv_prep(const float* __restrict__ swq, const unsigned* __restrict__ hdr,
                           float* __restrict__ mq, float* __restrict__ pwq) {
  int o = blockIdx.x * blockDim.x + threadIdx.x;
  if (o >= QKV_CH) return;
  float s_x = fmaxf(__uint_as_float(hdr[0]) / 127.0f, EPSF);
  float s_qkv = fmaxf(__uint_as_float(hdr[1]) / 127.0f, EPSF);
  float ns = (s_x * swq[o]) / s_qkv;
  int e;
  float f = frexpf(ns, &e);
  mq[o] = floorf(f * F2P31 + 0.5f);
  pwq[o] = exp2f((float)e - 31.0f);
}

// ---------------- requant qkv -> int8; Q,K in [bh][n][d]; V transposed [bh][d][m] pad 580 ----
__global__ void k_qkv_requant(const int* __restrict__ Cq, const float* __restrict__ swq,
                              const float* __restrict__ mq, const float* __restrict__ pwq,
                              const unsigned* __restrict__ hdr,
                              signed char* __restrict__ Q8, signed char* __restrict__ K8,
                              signed char* __restrict__ VT8) {
  float s_x = fmaxf(__uint_as_float(hdr[0]) / 127.0f, EPSF);
  int total = M_ROWS * QKV_CH;
  int stride = gridDim.x * blockDim.x;
  for (int i = blockIdx.x * blockDim.x + threadIdx.x; i < total; i += stride) {
    int o = i % QKV_CH;
    int bn = i / QKV_CH;
    float accs = s_x * swq[o];
    float qf = (float)Cq[i] * accs;
    float z = rintf(qf / accs);
    float t8 = rintf((z * mq[o]) * pwq[o]);
    t8 = fminf(fmaxf(t8, -128.f), 127.f);
    int s = o / CH;
    int rem = o - s * CH;
    int h = rem >> 6, d = rem & 63;
    int b = bn / SEQ, n = bn - b * SEQ;
    int bh = b * NH + h;
    signed char v = (signed char)t8;
    if (s == 0) Q8[(((size_t)bh * SEQ + n) << 6) + d] = v;
    else if (s == 1) K8[(((size_t)bh * SEQ + n) << 6) + d] = v;
    else VT8[(size_t)bh * (64 * VT_ROW) + (size_t)d * VT_ROW + n] = v;
  }
}

// ---------------- attention: 256 thr/block, (b,h) x 64-row query tile; K+Vt in LDS ----------
__global__ __launch_bounds__(256) void k_attn(
    const signed char* __restrict__ Q8, const signed char* __restrict__ K8,
    const signed char* __restrict__ VT8, const unsigned* __restrict__ hdr,
    int* __restrict__ ctxi, unsigned* __restrict__ gctx) {
  __shared__ int Ks[SEQ * KS_STRIDE];   // 39236 B, row stride 17 ints (conflict-free)
  __shared__ int Vs[64 * VT_WORDS];     // 37120 B, Vt[d][m] rows of 145 ints
  __shared__ int pbufw[4][VT_WORDS];    // 2320 B, per-wave packed probs
  int tid = threadIdx.x;
  int t = tid & 63, wid = tid >> 6;
  int bh = blockIdx.x / 10, qt = blockIdx.x - bh * 10;
  int b = bh / NH, h = bh - b * NH;
  int row0 = qt * 64;
  int row_end = min(row0 + 64, SEQ);

  const int* Kg = (const int*)(K8 + (size_t)bh * SEQ * 64);
  for (int i = tid; i < SEQ * 16; i += 256) {
    int r = i >> 4, w = i & 15;
    Ks[r * KS_STRIDE + w] = Kg[i];
  }
  const int* Vtg = (const int*)(VT8 + (size_t)bh * (64 * VT_ROW));
  for (int i = tid; i < 64 * VT_WORDS; i += 256) Vs[i] = Vtg[i];
  __syncthreads();

  float s_qkv = fmaxf(__uint_as_float(hdr[1]) / 127.0f, EPSF);
  float s_attn = (s_qkv * s_qkv) * 0.125f;   // D^-0.5 = 0.125 exact
  float x0 = floorf(-1.0f / s_attn);
  float nx0 = 15.0f * x0;
  float pre_s = 0.0078125f * s_qkv;          // s_sm * s_qkv
  float avmax = 0.f;
  const int* vrow = Vs + t * VT_WORDS;
  const int* pw = pbufw[wid];
  unsigned char* pb = (unsigned char*)pbufw[wid];

  for (int n = row0 + wid; n < row_end; n += 4) {
    const int4* qp = (const int4*)(Q8 + (((size_t)bh * SEQ + n) << 6));
    int4 q0 = qp[0], q1 = qp[1], q2 = qp[2], q3 = qp[3];
    int q[16] = {q0.x, q0.y, q0.z, q0.w, q1.x, q1.y, q1.z, q1.w,
                 q2.x, q2.y, q2.z, q2.w, q3.x, q3.y, q3.z, q3.w};
    int sv[10];
    int lmax = -2147483647 - 1;
#pragma unroll
    for (int u = 0; u < 10; ++u) {
      int m = t + 64 * u;
      if (m < SEQ) {
        const int* kr = Ks + m * KS_STRIDE;
        int acc = 0;
#pragma unroll
        for (int k = 0; k < 16; ++k) acc = dot4(q[k], kr[k], acc);
        sv[u] = acc;
        lmax = max(lmax, acc);
      }
    }
#pragma unroll
    for (int off = 32; off; off >>= 1) lmax = max(lmax, __shfl_xor(lmax, off, 64));

    float ei[10];
    double dsum = 0.0;
#pragma unroll
    for (int u = 0; u < 10; ++u) {
      int m = t + 64 * u;
      if (m < SEQ) {
        float xi = (float)(sv[u] - lmax);
        xi = xi + floorf(xi * 0.5f) - floorf(xi * 0.0625f);  // exact pow2 ops
        xi = fmaxf(xi, nx0);
        float qd = floorf(xi / x0);
        float r = xi - x0 * qd;
        float e = floorf((r * 0.5f - x0) * exp2f(15.0f - qd));
        e = fmaxf(e, 0.0f);
        ei[u] = e;
        dsum += (double)e;  // exact ints; clamp margin ~30x so order-safe
      }
    }
#pragma unroll
    for (int off = 32; off; off >>= 1) dsum += __shfl_xor(dsum, off, 64);
    float esum = fminf((float)dsum, F2P31);
    float factor = floorf(F2P31 / esum);
#pragma unroll
    for (int u = 0; u < 10; ++u) {
      int m = t + 64 * u;
      if (m < SEQ)
        pb[m] = (unsigned char)(int)floorf((ei[u] * factor) * 5.9604644775390625e-08f);
      else if (m < VT_ROW)
        pb[m] = 0;   // zero pad so poisoned Vt pad bytes contribute 0
    }
    __threadfence_block();
    int cacc = 0;
#pragma unroll 5
    for (int j = 0; j < VT_WORDS; ++j) cacc = dot4(pw[j], vrow[j], cacc);
    ctxi[((size_t)(b * SEQ + n)) * CH + h * 64 + t] = cacc;
    avmax = fmaxf(avmax, fabsf((float)cacc * pre_s));
    __threadfence_block();  // order PV reads before next row's pack writes
  }
#pragma unroll
  for (int off = 32; off; off >>= 1) avmax = fmaxf(avmax, __shfl_xor(avmax, off, 64));
  if (t == 0) atomicMax(gctx, __float_as_uint(avmax));
}

// ---------------- requant ctx -> int8 ----------------
__global__ void k_ctx_requant(const int* __restrict__ ctxi, const unsigned* __restrict__ hdr,
                              signed char* __restrict__ C8) {
  float s_qkv = fmaxf(__uint_as_float(hdr[1]) / 127.0f, EPSF);
  float pre_s = 0.0078125f * s_qkv;
  float s_ctx = fmaxf(__uint_as_float(hdr[2]) / 127.0f, EPSF);
  float ns = pre_s / s_ctx;
  int e;
  float f = frexpf(ns, &e);
  float mm = floorf(f * F2P31 + 0.5f);
  float pw = exp2f((float)e - 31.0f);
  int total = M_ROWS * CH;
  int stride = gridDim.x * blockDim.x;
  for (int i = blockIdx.x * blockDim.x + threadIdx.x; i < total; i += stride) {
    float cf = (float)ctxi[i] * pre_s;
    float z = rintf(cf / pre_s);
    float t8 = rintf((z * mm) * pw);
    t8 = fminf(fmaxf(t8, -128.f), 127.f);
    C8[i] = (signed char)t8;
  }
}

// ---------------- GEMM2: out = (C8[M,K]*WP8[N,K]^T + rint(b/out_s)) * out_s ----------------
__global__ __launch_bounds__(256) void k_gemm_out(
    const signed char* __restrict__ A, const signed char* __restrict__ Bm,
    const float* __restrict__ swp, const float* __restrict__ bias,
    const unsigned* __restrict__ hdr, float* __restrict__ outp) {
  const int K = CH, Nc = CH, M = M_ROWS;
  __shared__ int As[64][9];
  __shared__ int Bs[64][9];
  int tx = threadIdx.x & 15;
  int ty = threadIdx.x >> 4;
  int row0 = blockIdx.y * 64;
  int col0 = blockIdx.x * 64;
  int acc[4][4] = {};
  for (int k0 = 0; k0 < K; k0 += 32) {
    for (int l = threadIdx.x; l < 512; l += 256) {
      int r = l >> 3, c = l & 7;
      int rg = row0 + r;
      As[r][c] = (rg < M) ? *(const int*)(A + (size_t)rg * K + k0 + (c << 2)) : 0;
      Bs[r][c] = *(const int*)(Bm + (size_t)(col0 + r) * K + k0 + (c << 2));
    }
    __syncthreads();
#pragma unroll
    for (int kk = 0; kk < 8; ++kk) {
      int a[4], b[4];
#pragma unroll
      for (int i = 0; i < 4; ++i) a[i] = As[ty * 4 + i][kk];
#pragma unroll
      for (int j = 0; j < 4; ++j) b[j] = Bs[tx * 4 + j][kk];
#pragma unroll
      for (int i = 0; i < 4; ++i)
#pragma unroll
        for (int j = 0; j < 4; ++j) acc[i][j] = dot4(a[i], b[j], acc[i][j]);
    }
    __syncthreads();
  }
  float s_ctx = fmaxf(__uint_as_float(hdr[2]) / 127.0f, EPSF);
  for (int i = 0; i < 4; ++i) {
    int r = row0 + ty * 4 + i;
    if (r >= M) continue;
    for (int j = 0; j < 4; ++j) {
      int c = col0 + tx * 4 + j;
      float outs = s_ctx * swp[c];
      int bint = (int)rintf(bias[c] / outs);
      outp[(size_t)r * Nc + c] = (float)(acc[i][j] + bint) * outs;
    }
  }
}

extern "C" void kernel_launch(void* const* d_in, const int* in_sizes, int n_in,
                              void* d_out, int out_size, void* d_ws, size_t ws_size,
                              hipStream_t stream) {
  const float* x = (const float*)d_in[0];
  const float* w_qkv = (const float*)d_in[1];
  const float* b_qkv = (const float*)d_in[2];
  const float* w_proj = (const float*)d_in[3];
  const float* b_proj = (const float*)d_in[4];
  float* outp = (float*)d_out;

  // ---- workspace: bump allocator, 4 KB aligned ----
  char* ws = (char*)d_ws;
  size_t off = 0;
  auto alloc = [&](size_t sz) -> char* {
    char* p = ws + off;
    off = (off + sz + 4095) & ~(size_t)4095;
    return p;
  };
  unsigned* hdr = (unsigned*)alloc(256);   // [0]=max|x| [1]=max|qkv_f| [2]=max|ctx_f|
  float* SWQ = (float*)alloc(QKV_CH * 4);
  float* SWP = (float*)alloc(CH * 4);
  float* MQ  = (float*)alloc(QKV_CH * 4);
  float* PWQ = (float*)alloc(QKV_CH * 4);
  signed char* WQ8 = (signed char*)alloc((size_t)QKV_CH * CH);
  signed char* WP8 = (signed char*)alloc((size_t)CH * CH);
  signed char* X8  = (signed char*)alloc((size_t)M_ROWS * CH);
  signed char* Q8  = (signed char*)alloc((size_t)M_ROWS * CH);
  signed char* K8  = (signed char*)alloc((size_t)M_ROWS * CH);
  signed char* VT8 = (signed char*)alloc((size_t)BQ * NH * 64 * VT_ROW);
  signed char* C8  = (signed char*)alloc((size_t)M_ROWS * CH);
  int* QKVI = (int*)alloc((size_t)M_ROWS * QKV_CH * 4);
  int* CTXI = (int*)alloc((size_t)M_ROWS * CH * 4);
  (void)ws_size;

  hipMemsetAsync(hdr, 0, 256, stream);
  int nx = BQ * SEQ * CH;
  k_absmax<<<1024, 256, 0, stream>>>(x, nx, hdr + 0);
  k_wquant<<<QKV_CH, 256, 0, stream>>>(w_qkv, CH, WQ8, SWQ);
  k_wquant<<<CH, 256, 0, stream>>>(w_proj, CH, WP8, SWP);
  k_aquant<<<2048, 256, 0, stream>>>(x, nx, hdr, X8);
  dim3 g1(QKV_CH / 64, (M_ROWS + 63) / 64);
  k_gemm_qkv<<<g1, 256, 0, stream>>>(X8, WQ8, SWQ, b_qkv, hdr, QKVI, hdr + 1);
  k_qkv_prep<<<(QKV_CH + 255) / 256, 256, 0, stream>>>(SWQ, hdr, MQ, PWQ);
  k_qkv_requant<<<2048, 256, 0, stream>>>(QKVI, SWQ, MQ, PWQ, hdr, Q8, K8, VT8);
  k_attn<<<BQ * NH * 10, 256, 0, stream>>>(Q8, K8, VT8, hdr, CTXI, hdr + 2);
  k_ctx_requant<<<2048, 256, 0, stream>>>(CTXI, hdr, C8);
  dim3 g2(CH / 64, (M_ROWS + 63) / 64);
  k_gemm_out<<<g2, 256, 0, stream>>>(C8, WP8, SWP, b_proj, hdr, outp);
}

// Round 4
// 388.279 us; speedup vs baseline: 2.4615x; 1.2444x over previous
//
#include <hip/hip_runtime.h>
#include <math.h>

// Problem constants
#define BQ 8
#define SEQ 577
#define CH 768
#define NH 12
#define HD 64
#define M_ROWS (BQ * SEQ)      // 4616
#define QKV_CH (3 * CH)        // 2304
#define EPSF 1.1920929e-07f
#define F2P31 2147483648.0f    // float32(2^31 - 1) rounds to 2^31 -- replicate jnp

#define VT_ROW 640             // Vt row bytes (577 padded, 64B-aligned rows)
#define P_STRIDE 664           // P LDS row stride bytes (166 words -> 4-way max conflicts)

typedef __attribute__((ext_vector_type(4))) int i32x4;

#if defined(__has_builtin)
#  if __has_builtin(__builtin_amdgcn_sdot4)
#    define HAVE_SDOT4 1
#  endif
#endif

__device__ __forceinline__ int dot4(int a, int b, int c) {
#ifdef HAVE_SDOT4
  return __builtin_amdgcn_sdot4(a, b, c, false);
#else
  c += (int)(signed char)(a)       * (int)(signed char)(b);
  c += (int)(signed char)(a >> 8)  * (int)(signed char)(b >> 8);
  c += (int)(signed char)(a >> 16) * (int)(signed char)(b >> 16);
  c += (int)(signed char)(a >> 24) * (int)(signed char)(b >> 24);
  return c;
#endif
}

// ---------------- global abs-max of a float tensor (exact, order-independent) --------
__global__ void k_absmax(const float* __restrict__ x, int n, unsigned* __restrict__ gmax) {
  float m = 0.f;
  int stride = gridDim.x * blockDim.x;
  for (int i = blockIdx.x * blockDim.x + threadIdx.x; i < n; i += stride)
    m = fmaxf(m, fabsf(x[i]));
#pragma unroll
  for (int off = 32; off; off >>= 1) m = fmaxf(m, __shfl_xor(m, off, 64));
  __shared__ float red[4];
  if ((threadIdx.x & 63) == 0) red[threadIdx.x >> 6] = m;
  __syncthreads();
  if (threadIdx.x == 0) {
    float mm = red[0];
    for (int i = 1; i < (int)(blockDim.x >> 6); ++i) mm = fmaxf(mm, red[i]);
    atomicMax(gmax, __float_as_uint(mm));
  }
}

// ---------------- per-row weight quant ----------------
__global__ void k_wquant(const float* __restrict__ w, int K,
                         signed char* __restrict__ w8, float* __restrict__ sw) {
  int row = blockIdx.x;
  const float* wr = w + (size_t)row * K;
  float m = 0.f;
  for (int c = threadIdx.x; c < K; c += blockDim.x) m = fmaxf(m, fabsf(wr[c]));
#pragma unroll
  for (int off = 32; off; off >>= 1) m = fmaxf(m, __shfl_xor(m, off, 64));
  __shared__ float red[4];
  if ((threadIdx.x & 63) == 0) red[threadIdx.x >> 6] = m;
  __syncthreads();
  float mm = fmaxf(fmaxf(red[0], red[1]), fmaxf(red[2], red[3]));
  float s = fmaxf(mm / 127.0f, EPSF);
  if (threadIdx.x == 0) sw[row] = s;
  for (int c = threadIdx.x; c < K; c += blockDim.x) {
    float q = rintf(wr[c] / s);
    q = fminf(fmaxf(q, -128.f), 127.f);
    w8[(size_t)row * K + c] = (signed char)q;
  }
}

// ---------------- per-tensor activation quant ----------------
__global__ void k_aquant(const float* __restrict__ x, int n,
                         const unsigned* __restrict__ hdr, signed char* __restrict__ x8) {
  float s = fmaxf(__uint_as_float(hdr[0]) / 127.0f, EPSF);
  int stride = gridDim.x * blockDim.x;
  for (int i = blockIdx.x * blockDim.x + threadIdx.x; i < n; i += stride) {
    float q = rintf(x[i] / s);
    q = fminf(fmaxf(q, -128.f), 127.f);
    x8[i] = (signed char)q;
  }
}

// ---------------- GEMM1: qkv_int = X8[M,K] * WQ8[N,K]^T + rint(bias/acc_s); track max|qkv_f| ----
__global__ __launch_bounds__(256) void k_gemm_qkv(
    const signed char* __restrict__ A, const signed char* __restrict__ Bm,
    const float* __restrict__ swq, const float* __restrict__ bias,
    const unsigned* __restrict__ hdr, int* __restrict__ Cq, unsigned* __restrict__ gq) {
  const int K = CH, Nc = QKV_CH, M = M_ROWS;
  __shared__ int As[64][9];
  __shared__ int Bs[64][9];
  __shared__ float red[4];
  int tx = threadIdx.x & 15;
  int ty = threadIdx.x >> 4;
  int row0 = blockIdx.y * 64;
  int col0 = blockIdx.x * 64;
  int acc[4][4] = {};
  for (int k0 = 0; k0 < K; k0 += 32) {
    for (int l = threadIdx.x; l < 512; l += 256) {
      int r = l >> 3, c = l & 7;
      int rg = row0 + r;
      As[r][c] = (rg < M) ? *(const int*)(A + (size_t)rg * K + k0 + (c << 2)) : 0;
      Bs[r][c] = *(const int*)(Bm + (size_t)(col0 + r) * K + k0 + (c << 2));
    }
    __syncthreads();
#pragma unroll
    for (int kk = 0; kk < 8; ++kk) {
      int a[4], b[4];
#pragma unroll
      for (int i = 0; i < 4; ++i) a[i] = As[ty * 4 + i][kk];
#pragma unroll
      for (int j = 0; j < 4; ++j) b[j] = Bs[tx * 4 + j][kk];
#pragma unroll
      for (int i = 0; i < 4; ++i)
#pragma unroll
        for (int j = 0; j < 4; ++j) acc[i][j] = dot4(a[i], b[j], acc[i][j]);
    }
    __syncthreads();
  }
  float s_x = fmaxf(__uint_as_float(hdr[0]) / 127.0f, EPSF);
  float lmax = 0.f;
  for (int i = 0; i < 4; ++i) {
    int r = row0 + ty * 4 + i;
    if (r >= M) continue;
    for (int j = 0; j < 4; ++j) {
      int c = col0 + tx * 4 + j;
      float accs = s_x * swq[c];
      int bint = (int)rintf(bias[c] / accs);
      int qv = acc[i][j] + bint;
      Cq[(size_t)r * Nc + c] = qv;
      lmax = fmaxf(lmax, fabsf((float)qv * accs));
    }
  }
#pragma unroll
  for (int off = 32; off; off >>= 1) lmax = fmaxf(lmax, __shfl_xor(lmax, off, 64));
  if ((threadIdx.x & 63) == 0) red[threadIdx.x >> 6] = lmax;
  __syncthreads();
  if (threadIdx.x == 0)
    atomicMax(gq, __float_as_uint(fmaxf(fmaxf(red[0], red[1]), fmaxf(red[2], red[3]))));
}

// ---------------- per-channel fixedpoint requant constants for qkv ----------------
__global__ void k_qkv_prep(const float* __restrict__ swq, const unsigned* __restrict__ hdr,
                           float* __restrict__ mq, float* __restrict__ pwq) {
  int o = blockIdx.x * blockDim.x + threadIdx.x;
  if (o >= QKV_CH) return;
  float s_x = fmaxf(__uint_as_float(hdr[0]) / 127.0f, EPSF);
  float s_qkv = fmaxf(__uint_as_float(hdr[1]) / 127.0f, EPSF);
  float ns = (s_x * swq[o]) / s_qkv;
  int e;
  float f = frexpf(ns, &e);
  mq[o] = floorf(f * F2P31 + 0.5f);
  pwq[o] = exp2f((float)e - 31.0f);
}

// ---------------- requant qkv -> int8; Q,K in [bh][n][d]; V transposed [bh][d][m] pad 640 ----
__global__ void k_qkv_requant(const int* __restrict__ Cq, const float* __restrict__ swq,
                              const float* __restrict__ mq, const float* __restrict__ pwq,
                              const unsigned* __restrict__ hdr,
                              signed char* __restrict__ Q8, signed char* __restrict__ K8,
                              signed char* __restrict__ VT8) {
  float s_x = fmaxf(__uint_as_float(hdr[0]) / 127.0f, EPSF);
  int total = M_ROWS * QKV_CH;
  int stride = gridDim.x * blockDim.x;
  for (int i = blockIdx.x * blockDim.x + threadIdx.x; i < total; i += stride) {
    int o = i % QKV_CH;
    int bn = i / QKV_CH;
    float accs = s_x * swq[o];
    float qf = (float)Cq[i] * accs;
    float z = rintf(qf / accs);
    float t8 = rintf((z * mq[o]) * pwq[o]);
    t8 = fminf(fmaxf(t8, -128.f), 127.f);
    int s = o / CH;
    int rem = o - s * CH;
    int h = rem >> 6, d = rem & 63;
    int b = bn / SEQ, n = bn - b * SEQ;
    int bh = b * NH + h;
    signed char v = (signed char)t8;
    if (s == 0) Q8[(((size_t)bh * SEQ + n) << 6) + d] = v;
    else if (s == 1) K8[(((size_t)bh * SEQ + n) << 6) + d] = v;
    else VT8[(size_t)bh * (64 * VT_ROW) + (size_t)d * VT_ROW + n] = v;
  }
}

// ---------------- attention: 1 wave per (bh, 16-query tile), i8 MFMA QK + PV -------------
__global__ __launch_bounds__(64, 2) void k_attn(
    const signed char* __restrict__ Q8, const signed char* __restrict__ K8,
    const signed char* __restrict__ VT8, const unsigned* __restrict__ hdr,
    int* __restrict__ ctxi, unsigned* __restrict__ gctx) {
  __shared__ unsigned char P[16 * P_STRIDE];   // probs [row][m], m-contiguous for A-frags
  int t = threadIdx.x;
  int qt = blockIdx.x, bh = blockIdx.y;
  int b = bh / NH, h = bh - b * NH;
  int col = t & 15, q4 = t >> 4;

  // zero P pad region m in [576, 640) for every row (V pad garbage * 0 = 0)
  for (int i = t; i < 16 * 16; i += 64) {
    int r = i >> 4, w = i & 15;
    *(int*)&P[r * P_STRIDE + 576 + (w << 2)] = 0;
  }

  // Q A-fragment: A[m=lane&15][k=(lane>>4)*8+j]; two halves of d (K=32 each)
  const signed char* Qb = Q8 + (((size_t)bh * SEQ + qt * 16 + col) << 6);
  long qa0 = *(const long*)(Qb + q4 * 8);
  long qa1 = *(const long*)(Qb + 32 + q4 * 8);

  // ---- QK^T: 37 kv tiles, logits kept in registers (C-layout) ----
  const signed char* Kb = K8 + ((size_t)bh * SEQ << 6);
  i32x4 sv[37];
#pragma unroll
  for (int kt = 0; kt < 37; ++kt) {
    const signed char* kr = Kb + ((size_t)(kt * 16 + col) << 6);
    long kb0 = *(const long*)(kr + q4 * 8);
    long kb1 = *(const long*)(kr + 32 + q4 * 8);
    i32x4 a = {0, 0, 0, 0};
    a = __builtin_amdgcn_mfma_i32_16x16x32_i8(qa0, kb0, a, 0, 0, 0);
    a = __builtin_amdgcn_mfma_i32_16x16x32_i8(qa1, kb1, a, 0, 0, 0);
    sv[kt] = a;
  }

  // ---- per-row max over kv (row = q4*4+reg, col = lane&15; reduce over low-4 lane bits) ----
  int mx[4] = {-2147483647 - 1, -2147483647 - 1, -2147483647 - 1, -2147483647 - 1};
#pragma unroll
  for (int kt = 0; kt < 37; ++kt) {
    bool valid = (kt < 36) | (col < 1);
#pragma unroll
    for (int r = 0; r < 4; ++r)
      if (valid) mx[r] = max(mx[r], sv[kt][r]);
  }
#pragma unroll
  for (int r = 0; r < 4; ++r) {
    mx[r] = max(mx[r], __shfl_xor(mx[r], 1, 64));
    mx[r] = max(mx[r], __shfl_xor(mx[r], 2, 64));
    mx[r] = max(mx[r], __shfl_xor(mx[r], 4, 64));
    mx[r] = max(mx[r], __shfl_xor(mx[r], 8, 64));
  }

  // ---- integer shiftmax (op-for-op identical to verified R3 path) ----
  float s_qkv = fmaxf(__uint_as_float(hdr[1]) / 127.0f, EPSF);
  float s_attn = (s_qkv * s_qkv) * 0.125f;
  float x0 = floorf(-1.0f / s_attn);
  float nx0 = 15.0f * x0;
  double dsum[4] = {0.0, 0.0, 0.0, 0.0};
#pragma unroll
  for (int kt = 0; kt < 37; ++kt) {
    bool valid = (kt < 36) | (col < 1);
#pragma unroll
    for (int r = 0; r < 4; ++r) {
      float xi = (float)(sv[kt][r] - mx[r]);
      xi = xi + floorf(xi * 0.5f) - floorf(xi * 0.0625f);
      xi = fmaxf(xi, nx0);
      float qd = floorf(xi / x0);
      float rr = xi - x0 * qd;
      float e = floorf((rr * 0.5f - x0) * exp2f(15.0f - qd));
      e = fmaxf(e, 0.0f);
      e = valid ? e : 0.0f;
      dsum[r] += (double)e;        // exact ints, order-free
      sv[kt][r] = __float_as_int(e);
    }
  }
  float fac[4];
#pragma unroll
  for (int r = 0; r < 4; ++r) {
    double d = dsum[r];
    d += __shfl_xor(d, 1, 64);
    d += __shfl_xor(d, 2, 64);
    d += __shfl_xor(d, 4, 64);
    d += __shfl_xor(d, 8, 64);
    float esum = fminf((float)d, F2P31);
    fac[r] = floorf(F2P31 / esum);
  }

  __syncthreads();  // order pad zeroing before byte pack (same addresses at kt=36)
  // ---- pack probs to LDS [row][m] bytes ----
#pragma unroll
  for (int kt = 0; kt < 37; ++kt) {
#pragma unroll
    for (int r = 0; r < 4; ++r) {
      float e = __int_as_float(sv[kt][r]);
      int p = (int)floorf((e * fac[r]) * 5.9604644775390625e-08f);  // /2^24 exact scale
      P[(q4 * 4 + r) * P_STRIDE + kt * 16 + col] = (unsigned char)p;
    }
  }
  __syncthreads();  // drain LDS writes before A-frag reads

  // ---- PV: D[row_q][d] = sum_m P[row_q][m] * V[m][d]; 20 m-chunks x 4 d-tiles ----
  const signed char* Vb = VT8 + (size_t)bh * (64 * VT_ROW);
  i32x4 acc2[4] = {{0,0,0,0}, {0,0,0,0}, {0,0,0,0}, {0,0,0,0}};
  for (int mc = 0; mc < 20; ++mc) {
    long pa = *(const long*)&P[col * P_STRIDE + mc * 32 + q4 * 8];
#pragma unroll
    for (int ct = 0; ct < 4; ++ct) {
      long vb = *(const long*)(Vb + (size_t)(ct * 16 + col) * VT_ROW + mc * 32 + q4 * 8);
      acc2[ct] = __builtin_amdgcn_mfma_i32_16x16x32_i8(pa, vb, acc2[ct], 0, 0, 0);
    }
  }

  // ---- store ctx (C-layout: row=q4*4+reg, col=d) + track max|ctx_f| ----
  float pre_s = 0.0078125f * s_qkv;  // s_sm * s_qkv (exact pow2)
  float avmax = 0.f;
#pragma unroll
  for (int r = 0; r < 4; ++r) {
    int n = qt * 16 + q4 * 4 + r;
    if (n < SEQ) {
#pragma unroll
      for (int ct = 0; ct < 4; ++ct) {
        int cacc = acc2[ct][r];
        ctxi[((size_t)(b * SEQ + n)) * CH + h * 64 + ct * 16 + col] = cacc;
        avmax = fmaxf(avmax, fabsf((float)cacc * pre_s));
      }
    }
  }
#pragma unroll
  for (int off = 32; off; off >>= 1) avmax = fmaxf(avmax, __shfl_xor(avmax, off, 64));
  if (t == 0) atomicMax(gctx, __float_as_uint(avmax));
}

// ---------------- requant ctx -> int8 ----------------
__global__ void k_ctx_requant(const int* __restrict__ ctxi, const unsigned* __restrict__ hdr,
                              signed char* __restrict__ C8) {
  float s_qkv = fmaxf(__uint_as_float(hdr[1]) / 127.0f, EPSF);
  float pre_s = 0.0078125f * s_qkv;
  float s_ctx = fmaxf(__uint_as_float(hdr[2]) / 127.0f, EPSF);
  float ns = pre_s / s_ctx;
  int e;
  float f = frexpf(ns, &e);
  float mm = floorf(f * F2P31 + 0.5f);
  float pw = exp2f((float)e - 31.0f);
  int total = M_ROWS * CH;
  int stride = gridDim.x * blockDim.x;
  for (int i = blockIdx.x * blockDim.x + threadIdx.x; i < total; i += stride) {
    float cf = (float)ctxi[i] * pre_s;
    float z = rintf(cf / pre_s);
    float t8 = rintf((z * mm) * pw);
    t8 = fminf(fmaxf(t8, -128.f), 127.f);
    C8[i] = (signed char)t8;
  }
}

// ---------------- GEMM2: out = (C8[M,K]*WP8[N,K]^T + rint(b/out_s)) * out_s ----------------
__global__ __launch_bounds__(256) void k_gemm_out(
    const signed char* __restrict__ A, const signed char* __restrict__ Bm,
    const float* __restrict__ swp, const float* __restrict__ bias,
    const unsigned* __restrict__ hdr, float* __restrict__ outp) {
  const int K = CH, Nc = CH, M = M_ROWS;
  __shared__ int As[64][9];
  __shared__ int Bs[64][9];
  int tx = threadIdx.x & 15;
  int ty = threadIdx.x >> 4;
  int row0 = blockIdx.y * 64;
  int col0 = blockIdx.x * 64;
  int acc[4][4] = {};
  for (int k0 = 0; k0 < K; k0 += 32) {
    for (int l = threadIdx.x; l < 512; l += 256) {
      int r = l >> 3, c = l & 7;
      int rg = row0 + r;
      As[r][c] = (rg < M) ? *(const int*)(A + (size_t)rg * K + k0 + (c << 2)) : 0;
      Bs[r][c] = *(const int*)(Bm + (size_t)(col0 + r) * K + k0 + (c << 2));
    }
    __syncthreads();
#pragma unroll
    for (int kk = 0; kk < 8; ++kk) {
      int a[4], b[4];
#pragma unroll
      for (int i = 0; i < 4; ++i) a[i] = As[ty * 4 + i][kk];
#pragma unroll
      for (int j = 0; j < 4; ++j) b[j] = Bs[tx * 4 + j][kk];
#pragma unroll
      for (int i = 0; i < 4; ++i)
#pragma unroll
        for (int j = 0; j < 4; ++j) acc[i][j] = dot4(a[i], b[j], acc[i][j]);
    }
    __syncthreads();
  }
  float s_ctx = fmaxf(__uint_as_float(hdr[2]) / 127.0f, EPSF);
  for (int i = 0; i < 4; ++i) {
    int r = row0 + ty * 4 + i;
    if (r >= M) continue;
    for (int j = 0; j < 4; ++j) {
      int c = col0 + tx * 4 + j;
      float outs = s_ctx * swp[c];
      int bint = (int)rintf(bias[c] / outs);
      outp[(size_t)r * Nc + c] = (float)(acc[i][j] + bint) * outs;
    }
  }
}

extern "C" void kernel_launch(void* const* d_in, const int* in_sizes, int n_in,
                              void* d_out, int out_size, void* d_ws, size_t ws_size,
                              hipStream_t stream) {
  const float* x = (const float*)d_in[0];
  const float* w_qkv = (const float*)d_in[1];
  const float* b_qkv = (const float*)d_in[2];
  const float* w_proj = (const float*)d_in[3];
  const float* b_proj = (const float*)d_in[4];
  float* outp = (float*)d_out;

  // ---- workspace: bump allocator, 4 KB aligned ----
  char* ws = (char*)d_ws;
  size_t off = 0;
  auto alloc = [&](size_t sz) -> char* {
    char* p = ws + off;
    off = (off + sz + 4095) & ~(size_t)4095;
    return p;
  };
  unsigned* hdr = (unsigned*)alloc(256);   // [0]=max|x| [1]=max|qkv_f| [2]=max|ctx_f|
  float* SWQ = (float*)alloc(QKV_CH * 4);
  float* SWP = (float*)alloc(CH * 4);
  float* MQ  = (float*)alloc(QKV_CH * 4);
  float* PWQ = (float*)alloc(QKV_CH * 4);
  signed char* WQ8 = (signed char*)alloc((size_t)QKV_CH * CH);
  signed char* WP8 = (signed char*)alloc((size_t)CH * CH);
  signed char* X8  = (signed char*)alloc((size_t)M_ROWS * CH);
  signed char* Q8  = (signed char*)alloc((size_t)M_ROWS * CH);
  signed char* K8  = (signed char*)alloc((size_t)M_ROWS * CH);
  signed char* VT8 = (signed char*)alloc((size_t)BQ * NH * 64 * VT_ROW);
  signed char* C8  = (signed char*)alloc((size_t)M_ROWS * CH);
  int* QKVI = (int*)alloc((size_t)M_ROWS * QKV_CH * 4);
  int* CTXI = (int*)alloc((size_t)M_ROWS * CH * 4);
  (void)ws_size;

  hipMemsetAsync(hdr, 0, 256, stream);
  int nx = BQ * SEQ * CH;
  k_absmax<<<1024, 256, 0, stream>>>(x, nx, hdr + 0);
  k_wquant<<<QKV_CH, 256, 0, stream>>>(w_qkv, CH, WQ8, SWQ);
  k_wquant<<<CH, 256, 0, stream>>>(w_proj, CH, WP8, SWP);
  k_aquant<<<2048, 256, 0, stream>>>(x, nx, hdr, X8);
  dim3 g1(QKV_CH / 64, (M_ROWS + 63) / 64);
  k_gemm_qkv<<<g1, 256, 0, stream>>>(X8, WQ8, SWQ, b_qkv, hdr, QKVI, hdr + 1);
  k_qkv_prep<<<(QKV_CH + 255) / 256, 256, 0, stream>>>(SWQ, hdr, MQ, PWQ);
  k_qkv_requant<<<2048, 256, 0, stream>>>(QKVI, SWQ, MQ, PWQ, hdr, Q8, K8, VT8);
  dim3 ga(37, BQ * NH);
  k_attn<<<ga, 64, 0, stream>>>(Q8, K8, VT8, hdr, CTXI, hdr + 2);
  k_ctx_requant<<<2048, 256, 0, stream>>>(CTXI, hdr, C8);
  dim3 g2(CH / 64, (M_ROWS + 63) / 64);
  k_gemm_out<<<g2, 256, 0, stream>>>(C8, WP8, SWP, b_proj, hdr, outp);
}

// Round 5
// 295.828 us; speedup vs baseline: 3.2307x; 1.3125x over previous
//
#include <hip/hip_runtime.h>
#include <math.h>

// Problem constants
#define BQ 8
#define SEQ 577
#define CH 768
#define NH 12
#define HD 64
#define M_ROWS (BQ * SEQ)      // 4616
#define QKV_CH (3 * CH)        // 2304
#define EPSF 1.1920929e-07f
#define F2P31 2147483648.0f    // float32(2^31 - 1) rounds to 2^31 -- replicate jnp

#define VT_ROW 640             // Vt row bytes (577 padded, 64B-aligned rows)
#define P_STRIDE 664           // P LDS row stride bytes

typedef __attribute__((ext_vector_type(4))) int i32x4;
typedef struct __align__(16) { long x, y; } L2T;

#if defined(__has_builtin)
#  if __has_builtin(__builtin_amdgcn_sdot4)
#    define HAVE_SDOT4 1
#  endif
#endif

__device__ __forceinline__ int dot4(int a, int b, int c) {
#ifdef HAVE_SDOT4
  return __builtin_amdgcn_sdot4(a, b, c, false);
#else
  c += (int)(signed char)(a)       * (int)(signed char)(b);
  c += (int)(signed char)(a >> 8)  * (int)(signed char)(b >> 8);
  c += (int)(signed char)(a >> 16) * (int)(signed char)(b >> 16);
  c += (int)(signed char)(a >> 24) * (int)(signed char)(b >> 24);
  return c;
#endif
}

// ---------------- global abs-max of a float tensor (exact, order-independent) --------
__global__ void k_absmax(const float* __restrict__ x, int n, unsigned* __restrict__ gmax) {
  float m = 0.f;
  int stride = gridDim.x * blockDim.x;
  for (int i = blockIdx.x * blockDim.x + threadIdx.x; i < n; i += stride)
    m = fmaxf(m, fabsf(x[i]));
#pragma unroll
  for (int off = 32; off; off >>= 1) m = fmaxf(m, __shfl_xor(m, off, 64));
  __shared__ float red[4];
  if ((threadIdx.x & 63) == 0) red[threadIdx.x >> 6] = m;
  __syncthreads();
  if (threadIdx.x == 0) {
    float mm = red[0];
    for (int i = 1; i < (int)(blockDim.x >> 6); ++i) mm = fmaxf(mm, red[i]);
    atomicMax(gmax, __float_as_uint(mm));
  }
}

// ---------------- per-row weight quant ----------------
__global__ void k_wquant(const float* __restrict__ w, int K,
                         signed char* __restrict__ w8, float* __restrict__ sw) {
  int row = blockIdx.x;
  const float* wr = w + (size_t)row * K;
  float m = 0.f;
  for (int c = threadIdx.x; c < K; c += blockDim.x) m = fmaxf(m, fabsf(wr[c]));
#pragma unroll
  for (int off = 32; off; off >>= 1) m = fmaxf(m, __shfl_xor(m, off, 64));
  __shared__ float red[4];
  if ((threadIdx.x & 63) == 0) red[threadIdx.x >> 6] = m;
  __syncthreads();
  float mm = fmaxf(fmaxf(red[0], red[1]), fmaxf(red[2], red[3]));
  float s = fmaxf(mm / 127.0f, EPSF);
  if (threadIdx.x == 0) sw[row] = s;
  for (int c = threadIdx.x; c < K; c += blockDim.x) {
    float q = rintf(wr[c] / s);
    q = fminf(fmaxf(q, -128.f), 127.f);
    w8[(size_t)row * K + c] = (signed char)q;
  }
}

// ---------------- per-tensor activation quant ----------------
__global__ void k_aquant(const float* __restrict__ x, int n,
                         const unsigned* __restrict__ hdr, signed char* __restrict__ x8) {
  float s = fmaxf(__uint_as_float(hdr[0]) / 127.0f, EPSF);
  int stride = gridDim.x * blockDim.x;
  for (int i = blockIdx.x * blockDim.x + threadIdx.x; i < n; i += stride) {
    float q = rintf(x[i] / s);
    q = fminf(fmaxf(q, -128.f), 127.f);
    x8[i] = (signed char)q;
  }
}

// ---- shared MFMA accumulate: 128x128 block tile, wave w does 64x64, frags from global ----
// A[M,K], B[N,K] both row-major K-contig i8, K=768. acc layout: C row=(q*4+reg), col=c.
__device__ __forceinline__ void mfma_gemm_core(
    const signed char* __restrict__ A, const signed char* __restrict__ Bm,
    int arow, int bcol, int c, int q, i32x4 acc[4][4]) {
  for (int k0 = 0; k0 < CH; k0 += 64) {
    L2T af[4], bf[4];
#pragma unroll
    for (int i = 0; i < 4; ++i)
      af[i] = *(const L2T*)(A + (size_t)(arow + i * 16 + c) * CH + k0 + q * 16);
#pragma unroll
    for (int j = 0; j < 4; ++j)
      bf[j] = *(const L2T*)(Bm + (size_t)(bcol + j * 16 + c) * CH + k0 + q * 16);
#pragma unroll
    for (int i = 0; i < 4; ++i)
#pragma unroll
      for (int j = 0; j < 4; ++j) {
        acc[i][j] = __builtin_amdgcn_mfma_i32_16x16x32_i8(af[i].x, bf[j].x, acc[i][j], 0, 0, 0);
        acc[i][j] = __builtin_amdgcn_mfma_i32_16x16x32_i8(af[i].y, bf[j].y, acc[i][j], 0, 0, 0);
      }
  }
}

// ---------------- GEMM1 (MFMA): qkv_int = X8*WQ8^T + rint(bias/acc_s); track max|qkv_f| ----
__global__ __launch_bounds__(256) void k_gemm_qkv(
    const signed char* __restrict__ A, const signed char* __restrict__ Bm,
    const float* __restrict__ swq, const float* __restrict__ bias,
    const unsigned* __restrict__ hdr, int* __restrict__ Cq, unsigned* __restrict__ gq) {
  __shared__ float red[4];
  int t = threadIdx.x;
  int lane = t & 63, w = t >> 6;
  int c = lane & 15, q = lane >> 4;
  int arow = blockIdx.y * 128 + (w & 1) * 64;
  int bcol = blockIdx.x * 128 + (w >> 1) * 64;
  i32x4 acc[4][4] = {};
  mfma_gemm_core(A, Bm, arow, bcol, c, q, acc);

  float s_x = fmaxf(__uint_as_float(hdr[0]) / 127.0f, EPSF);
  float lmax = 0.f;
#pragma unroll
  for (int j = 0; j < 4; ++j) {
    int ccol = bcol + j * 16 + c;
    float accs = s_x * swq[ccol];
    int bint = (int)rintf(bias[ccol] / accs);
#pragma unroll
    for (int i = 0; i < 4; ++i)
#pragma unroll
      for (int r = 0; r < 4; ++r) {
        int rr = arow + i * 16 + q * 4 + r;
        if (rr < M_ROWS) {
          int qv = acc[i][j][r] + bint;
          Cq[(size_t)rr * QKV_CH + ccol] = qv;
          lmax = fmaxf(lmax, fabsf((float)qv * accs));
        }
      }
  }
#pragma unroll
  for (int off = 32; off; off >>= 1) lmax = fmaxf(lmax, __shfl_xor(lmax, off, 64));
  if (lane == 0) red[w] = lmax;
  __syncthreads();
  if (t == 0)
    atomicMax(gq, __float_as_uint(fmaxf(fmaxf(red[0], red[1]), fmaxf(red[2], red[3]))));
}

// ---------------- per-channel fixedpoint requant constants for qkv ----------------
__global__ void k_qkv_prep(const float* __restrict__ swq, const unsigned* __restrict__ hdr,
                           float* __restrict__ mq, float* __restrict__ pwq) {
  int o = blockIdx.x * blockDim.x + threadIdx.x;
  if (o >= QKV_CH) return;
  float s_x = fmaxf(__uint_as_float(hdr[0]) / 127.0f, EPSF);
  float s_qkv = fmaxf(__uint_as_float(hdr[1]) / 127.0f, EPSF);
  float ns = (s_x * swq[o]) / s_qkv;
  int e;
  float f = frexpf(ns, &e);
  mq[o] = floorf(f * F2P31 + 0.5f);
  pwq[o] = exp2f((float)e - 31.0f);
}

// ---------------- requant qkv -> int8; Q,K in [bh][n][d]; V transposed [bh][d][m] pad 640 ----
__global__ void k_qkv_requant(const int* __restrict__ Cq, const float* __restrict__ swq,
                              const float* __restrict__ mq, const float* __restrict__ pwq,
                              const unsigned* __restrict__ hdr,
                              signed char* __restrict__ Q8, signed char* __restrict__ K8,
                              signed char* __restrict__ VT8) {
  float s_x = fmaxf(__uint_as_float(hdr[0]) / 127.0f, EPSF);
  int total = M_ROWS * QKV_CH;
  int stride = gridDim.x * blockDim.x;
  for (int i = blockIdx.x * blockDim.x + threadIdx.x; i < total; i += stride) {
    int o = i % QKV_CH;
    int bn = i / QKV_CH;
    float accs = s_x * swq[o];
    float qf = (float)Cq[i] * accs;
    float z = rintf(qf / accs);
    float t8 = rintf((z * mq[o]) * pwq[o]);
    t8 = fminf(fmaxf(t8, -128.f), 127.f);
    int s = o / CH;
    int rem = o - s * CH;
    int h = rem >> 6, d = rem & 63;
    int b = bn / SEQ, n = bn - b * SEQ;
    int bh = b * NH + h;
    signed char v = (signed char)t8;
    if (s == 0) Q8[(((size_t)bh * SEQ + n) << 6) + d] = v;
    else if (s == 1) K8[(((size_t)bh * SEQ + n) << 6) + d] = v;
    else VT8[(size_t)bh * (64 * VT_ROW) + (size_t)d * VT_ROW + n] = v;
  }
}

// ---------------- attention: 1 wave per (bh, 16-query tile), i8 MFMA QK + PV -------------
__global__ __launch_bounds__(64, 2) void k_attn(
    const signed char* __restrict__ Q8, const signed char* __restrict__ K8,
    const signed char* __restrict__ VT8, const unsigned* __restrict__ hdr,
    int* __restrict__ ctxi, unsigned* __restrict__ gctx) {
  __shared__ unsigned char P[16 * P_STRIDE];   // probs [row][m], m-contiguous for A-frags
  int t = threadIdx.x;
  int qt = blockIdx.x, bh = blockIdx.y;
  int b = bh / NH, h = bh - b * NH;
  int col = t & 15, q4 = t >> 4;

  // zero P pad region m in [576, 640) for every row (V pad garbage * 0 = 0)
  for (int i = t; i < 16 * 16; i += 64) {
    int r = i >> 4, w = i & 15;
    *(int*)&P[r * P_STRIDE + 576 + (w << 2)] = 0;
  }

  const signed char* Qb = Q8 + (((size_t)bh * SEQ + qt * 16 + col) << 6);
  long qa0 = *(const long*)(Qb + q4 * 8);
  long qa1 = *(const long*)(Qb + 32 + q4 * 8);

  // ---- QK^T: 37 kv tiles, logits kept in registers (C-layout) ----
  const signed char* Kb = K8 + ((size_t)bh * SEQ << 6);
  i32x4 sv[37];
#pragma unroll
  for (int kt = 0; kt < 37; ++kt) {
    const signed char* kr = Kb + ((size_t)(kt * 16 + col) << 6);
    long kb0 = *(const long*)(kr + q4 * 8);
    long kb1 = *(const long*)(kr + 32 + q4 * 8);
    i32x4 a = {0, 0, 0, 0};
    a = __builtin_amdgcn_mfma_i32_16x16x32_i8(qa0, kb0, a, 0, 0, 0);
    a = __builtin_amdgcn_mfma_i32_16x16x32_i8(qa1, kb1, a, 0, 0, 0);
    sv[kt] = a;
  }

  int mx[4] = {-2147483647 - 1, -2147483647 - 1, -2147483647 - 1, -2147483647 - 1};
#pragma unroll
  for (int kt = 0; kt < 37; ++kt) {
    bool valid = (kt < 36) | (col < 1);
#pragma unroll
    for (int r = 0; r < 4; ++r)
      if (valid) mx[r] = max(mx[r], sv[kt][r]);
  }
#pragma unroll
  for (int r = 0; r < 4; ++r) {
    mx[r] = max(mx[r], __shfl_xor(mx[r], 1, 64));
    mx[r] = max(mx[r], __shfl_xor(mx[r], 2, 64));
    mx[r] = max(mx[r], __shfl_xor(mx[r], 4, 64));
    mx[r] = max(mx[r], __shfl_xor(mx[r], 8, 64));
  }

  float s_qkv = fmaxf(__uint_as_float(hdr[1]) / 127.0f, EPSF);
  float s_attn = (s_qkv * s_qkv) * 0.125f;
  float x0 = floorf(-1.0f / s_attn);
  float nx0 = 15.0f * x0;
  double dsum[4] = {0.0, 0.0, 0.0, 0.0};
#pragma unroll
  for (int kt = 0; kt < 37; ++kt) {
    bool valid = (kt < 36) | (col < 1);
#pragma unroll
    for (int r = 0; r < 4; ++r) {
      float xi = (float)(sv[kt][r] - mx[r]);
      xi = xi + floorf(xi * 0.5f) - floorf(xi * 0.0625f);
      xi = fmaxf(xi, nx0);
      float qd = floorf(xi / x0);
      float rr = xi - x0 * qd;
      float e = floorf((rr * 0.5f - x0) * exp2f(15.0f - qd));
      e = fmaxf(e, 0.0f);
      e = valid ? e : 0.0f;
      dsum[r] += (double)e;
      sv[kt][r] = __float_as_int(e);
    }
  }
  float fac[4];
#pragma unroll
  for (int r = 0; r < 4; ++r) {
    double d = dsum[r];
    d += __shfl_xor(d, 1, 64);
    d += __shfl_xor(d, 2, 64);
    d += __shfl_xor(d, 4, 64);
    d += __shfl_xor(d, 8, 64);
    float esum = fminf((float)d, F2P31);
    fac[r] = floorf(F2P31 / esum);
  }

  __syncthreads();
#pragma unroll
  for (int kt = 0; kt < 37; ++kt) {
#pragma unroll
    for (int r = 0; r < 4; ++r) {
      float e = __int_as_float(sv[kt][r]);
      int p = (int)floorf((e * fac[r]) * 5.9604644775390625e-08f);
      P[(q4 * 4 + r) * P_STRIDE + kt * 16 + col] = (unsigned char)p;
    }
  }
  __syncthreads();

  const signed char* Vb = VT8 + (size_t)bh * (64 * VT_ROW);
  i32x4 acc2[4] = {{0,0,0,0}, {0,0,0,0}, {0,0,0,0}, {0,0,0,0}};
  for (int mc = 0; mc < 20; ++mc) {
    long pa = *(const long*)&P[col * P_STRIDE + mc * 32 + q4 * 8];
#pragma unroll
    for (int ct = 0; ct < 4; ++ct) {
      long vb = *(const long*)(Vb + (size_t)(ct * 16 + col) * VT_ROW + mc * 32 + q4 * 8);
      acc2[ct] = __builtin_amdgcn_mfma_i32_16x16x32_i8(pa, vb, acc2[ct], 0, 0, 0);
    }
  }

  float pre_s = 0.0078125f * s_qkv;
  float avmax = 0.f;
#pragma unroll
  for (int r = 0; r < 4; ++r) {
    int n = qt * 16 + q4 * 4 + r;
    if (n < SEQ) {
#pragma unroll
      for (int ct = 0; ct < 4; ++ct) {
        int cacc = acc2[ct][r];
        ctxi[((size_t)(b * SEQ + n)) * CH + h * 64 + ct * 16 + col] = cacc;
        avmax = fmaxf(avmax, fabsf((float)cacc * pre_s));
      }
    }
  }
#pragma unroll
  for (int off = 32; off; off >>= 1) avmax = fmaxf(avmax, __shfl_xor(avmax, off, 64));
  if (t == 0) atomicMax(gctx, __float_as_uint(avmax));
}

// ---------------- requant ctx -> int8 ----------------
__global__ void k_ctx_requant(const int* __restrict__ ctxi, const unsigned* __restrict__ hdr,
                              signed char* __restrict__ C8) {
  float s_qkv = fmaxf(__uint_as_float(hdr[1]) / 127.0f, EPSF);
  float pre_s = 0.0078125f * s_qkv;
  float s_ctx = fmaxf(__uint_as_float(hdr[2]) / 127.0f, EPSF);
  float ns = pre_s / s_ctx;
  int e;
  float f = frexpf(ns, &e);
  float mm = floorf(f * F2P31 + 0.5f);
  float pw = exp2f((float)e - 31.0f);
  int total = M_ROWS * CH;
  int stride = gridDim.x * blockDim.x;
  for (int i = blockIdx.x * blockDim.x + threadIdx.x; i < total; i += stride) {
    float cf = (float)ctxi[i] * pre_s;
    float z = rintf(cf / pre_s);
    float t8 = rintf((z * mm) * pw);
    t8 = fminf(fmaxf(t8, -128.f), 127.f);
    C8[i] = (signed char)t8;
  }
}

// ---------------- GEMM2 (MFMA): out = (C8*WP8^T + rint(b/out_s)) * out_s ----------------
__global__ __launch_bounds__(256) void k_gemm_out(
    const signed char* __restrict__ A, const signed char* __restrict__ Bm,
    const float* __restrict__ swp, const float* __restrict__ bias,
    const unsigned* __restrict__ hdr, float* __restrict__ outp) {
  int t = threadIdx.x;
  int lane = t & 63, w = t >> 6;
  int c = lane & 15, q = lane >> 4;
  int arow = blockIdx.y * 128 + (w & 1) * 64;
  int bcol = blockIdx.x * 128 + (w >> 1) * 64;
  i32x4 acc[4][4] = {};
  mfma_gemm_core(A, Bm, arow, bcol, c, q, acc);

  float s_ctx = fmaxf(__uint_as_float(hdr[2]) / 127.0f, EPSF);
#pragma unroll
  for (int j = 0; j < 4; ++j) {
    int ccol = bcol + j * 16 + c;
    float outs = s_ctx * swp[ccol];
    int bint = (int)rintf(bias[ccol] / outs);
#pragma unroll
    for (int i = 0; i < 4; ++i)
#pragma unroll
      for (int r = 0; r < 4; ++r) {
        int rr = arow + i * 16 + q * 4 + r;
        if (rr < M_ROWS)
          outp[(size_t)rr * CH + ccol] = (float)(acc[i][j][r] + bint) * outs;
      }
  }
}

extern "C" void kernel_launch(void* const* d_in, const int* in_sizes, int n_in,
                              void* d_out, int out_size, void* d_ws, size_t ws_size,
                              hipStream_t stream) {
  const float* x = (const float*)d_in[0];
  const float* w_qkv = (const float*)d_in[1];
  const float* b_qkv = (const float*)d_in[2];
  const float* w_proj = (const float*)d_in[3];
  const float* b_proj = (const float*)d_in[4];
  float* outp = (float*)d_out;

  // ---- workspace: bump allocator, 4 KB aligned ----
  char* ws = (char*)d_ws;
  size_t off = 0;
  auto alloc = [&](size_t sz) -> char* {
    char* p = ws + off;
    off = (off + sz + 4095) & ~(size_t)4095;
    return p;
  };
  unsigned* hdr = (unsigned*)alloc(256);   // [0]=max|x| [1]=max|qkv_f| [2]=max|ctx_f|
  float* SWQ = (float*)alloc(QKV_CH * 4);
  float* SWP = (float*)alloc(CH * 4);
  float* MQ  = (float*)alloc(QKV_CH * 4);
  float* PWQ = (float*)alloc(QKV_CH * 4);
  signed char* WQ8 = (signed char*)alloc((size_t)QKV_CH * CH);
  signed char* WP8 = (signed char*)alloc((size_t)CH * CH);
  // +128 rows padding: MFMA GEMM reads (but never writes) rows beyond M_ROWS
  signed char* X8  = (signed char*)alloc((size_t)(M_ROWS + 128) * CH);
  signed char* Q8  = (signed char*)alloc((size_t)M_ROWS * CH);
  signed char* K8  = (signed char*)alloc((size_t)M_ROWS * CH);
  signed char* VT8 = (signed char*)alloc((size_t)BQ * NH * 64 * VT_ROW);
  signed char* C8  = (signed char*)alloc((size_t)(M_ROWS + 128) * CH);
  int* QKVI = (int*)alloc((size_t)M_ROWS * QKV_CH * 4);
  int* CTXI = (int*)alloc((size_t)M_ROWS * CH * 4);
  (void)ws_size;

  hipMemsetAsync(hdr, 0, 256, stream);
  int nx = BQ * SEQ * CH;
  k_absmax<<<1024, 256, 0, stream>>>(x, nx, hdr + 0);
  k_wquant<<<QKV_CH, 256, 0, stream>>>(w_qkv, CH, WQ8, SWQ);
  k_wquant<<<CH, 256, 0, stream>>>(w_proj, CH, WP8, SWP);
  k_aquant<<<2048, 256, 0, stream>>>(x, nx, hdr, X8);
  dim3 g1(QKV_CH / 128, (M_ROWS + 127) / 128);
  k_gemm_qkv<<<g1, 256, 0, stream>>>(X8, WQ8, SWQ, b_qkv, hdr, QKVI, hdr + 1);
  k_qkv_prep<<<(QKV_CH + 255) / 256, 256, 0, stream>>>(SWQ, hdr, MQ, PWQ);
  k_qkv_requant<<<2048, 256, 0, stream>>>(QKVI, SWQ, MQ, PWQ, hdr, Q8, K8, VT8);
  dim3 ga(37, BQ * NH);
  k_attn<<<ga, 64, 0, stream>>>(Q8, K8, VT8, hdr, CTXI, hdr + 2);
  k_ctx_requant<<<2048, 256, 0, stream>>>(CTXI, hdr, C8);
  dim3 g2(CH / 128, (M_ROWS + 127) / 128);
  k_gemm_out<<<g2, 256, 0, stream>>>(C8, WP8, SWP, b_proj, hdr, outp);
}

// Round 6
// 293.863 us; speedup vs baseline: 3.2523x; 1.0067x over previous
//
#include <hip/hip_runtime.h>
#include <math.h>

// Problem constants
#define BQ 8
#define SEQ 577
#define CH 768
#define NH 12
#define HD 64
#define M_ROWS (BQ * SEQ)      // 4616
#define QKV_CH (3 * CH)        // 2304
#define EPSF 1.1920929e-07f
#define F2P31 2147483648.0f    // float32(2^31 - 1) rounds to 2^31 -- replicate jnp

#define VT_ROW 640             // Vt row bytes (577 padded, 64B-aligned rows)
#define P_STRIDE 664           // P LDS row stride bytes

typedef __attribute__((ext_vector_type(4))) int i32x4;
typedef struct __align__(16) { long x, y; } L2T;

#if defined(__has_builtin)
#  if __has_builtin(__builtin_amdgcn_sdot4)
#    define HAVE_SDOT4 1
#  endif
#endif

__device__ __forceinline__ int dot4(int a, int b, int c) {
#ifdef HAVE_SDOT4
  return __builtin_amdgcn_sdot4(a, b, c, false);
#else
  c += (int)(signed char)(a)       * (int)(signed char)(b);
  c += (int)(signed char)(a >> 8)  * (int)(signed char)(b >> 8);
  c += (int)(signed char)(a >> 16) * (int)(signed char)(b >> 16);
  c += (int)(signed char)(a >> 24) * (int)(signed char)(b >> 24);
  return c;
#endif
}

// shiftmax exp_int: bit-exact replication of reference f32 op sequence.
// exp2f(15-q) for integer q in [0,15] == 2^(15-q), built via exponent bits (exact).
__device__ __forceinline__ float softmax_e(int svr, int mxr, float x0, float nx0) {
  float xi = (float)(svr - mxr);
  xi = xi + floorf(xi * 0.5f) - floorf(xi * 0.0625f);  // exact pow2 ops on ints
  xi = fmaxf(xi, nx0);
  float qd = floorf(xi / x0);                          // correctly-rounded fdiv, as ref
  float rr = xi - x0 * qd;
  int qi = (int)qd;                                    // in [0,15]
  float p2 = __int_as_float((142 - qi) << 23);         // 2^(15-qi) exact
  float e = floorf((rr * 0.5f - x0) * p2);
  return fmaxf(e, 0.0f);
}

// ---------------- global abs-max of a float tensor (exact, order-independent) --------
__global__ void k_absmax(const float* __restrict__ x, int n, unsigned* __restrict__ gmax) {
  float m = 0.f;
  int stride = gridDim.x * blockDim.x;
  for (int i = blockIdx.x * blockDim.x + threadIdx.x; i < n; i += stride)
    m = fmaxf(m, fabsf(x[i]));
#pragma unroll
  for (int off = 32; off; off >>= 1) m = fmaxf(m, __shfl_xor(m, off, 64));
  __shared__ float red[4];
  if ((threadIdx.x & 63) == 0) red[threadIdx.x >> 6] = m;
  __syncthreads();
  if (threadIdx.x == 0) {
    float mm = red[0];
    for (int i = 1; i < (int)(blockDim.x >> 6); ++i) mm = fmaxf(mm, red[i]);
    atomicMax(gmax, __float_as_uint(mm));
  }
}

// ---------------- per-row weight quant ----------------
__global__ void k_wquant(const float* __restrict__ w, int K,
                         signed char* __restrict__ w8, float* __restrict__ sw) {
  int row = blockIdx.x;
  const float* wr = w + (size_t)row * K;
  float m = 0.f;
  for (int c = threadIdx.x; c < K; c += blockDim.x) m = fmaxf(m, fabsf(wr[c]));
#pragma unroll
  for (int off = 32; off; off >>= 1) m = fmaxf(m, __shfl_xor(m, off, 64));
  __shared__ float red[4];
  if ((threadIdx.x & 63) == 0) red[threadIdx.x >> 6] = m;
  __syncthreads();
  float mm = fmaxf(fmaxf(red[0], red[1]), fmaxf(red[2], red[3]));
  float s = fmaxf(mm / 127.0f, EPSF);
  if (threadIdx.x == 0) sw[row] = s;
  for (int c = threadIdx.x; c < K; c += blockDim.x) {
    float q = rintf(wr[c] / s);
    q = fminf(fmaxf(q, -128.f), 127.f);
    w8[(size_t)row * K + c] = (signed char)q;
  }
}

// ---------------- per-tensor activation quant ----------------
__global__ void k_aquant(const float* __restrict__ x, int n,
                         const unsigned* __restrict__ hdr, signed char* __restrict__ x8) {
  float s = fmaxf(__uint_as_float(hdr[0]) / 127.0f, EPSF);
  int stride = gridDim.x * blockDim.x;
  for (int i = blockIdx.x * blockDim.x + threadIdx.x; i < n; i += stride) {
    float q = rintf(x[i] / s);
    q = fminf(fmaxf(q, -128.f), 127.f);
    x8[i] = (signed char)q;
  }
}

// ---- shared MFMA accumulate: 128x128 block tile, wave w does 64x64, frags from global ----
__device__ __forceinline__ void mfma_gemm_core(
    const signed char* __restrict__ A, const signed char* __restrict__ Bm,
    int arow, int bcol, int c, int q, i32x4 acc[4][4]) {
  for (int k0 = 0; k0 < CH; k0 += 64) {
    L2T af[4], bf[4];
#pragma unroll
    for (int i = 0; i < 4; ++i)
      af[i] = *(const L2T*)(A + (size_t)(arow + i * 16 + c) * CH + k0 + q * 16);
#pragma unroll
    for (int j = 0; j < 4; ++j)
      bf[j] = *(const L2T*)(Bm + (size_t)(bcol + j * 16 + c) * CH + k0 + q * 16);
#pragma unroll
    for (int i = 0; i < 4; ++i)
#pragma unroll
      for (int j = 0; j < 4; ++j) {
        acc[i][j] = __builtin_amdgcn_mfma_i32_16x16x32_i8(af[i].x, bf[j].x, acc[i][j], 0, 0, 0);
        acc[i][j] = __builtin_amdgcn_mfma_i32_16x16x32_i8(af[i].y, bf[j].y, acc[i][j], 0, 0, 0);
      }
  }
}

// ---------------- GEMM1 (MFMA): qkv_int = X8*WQ8^T + rint(bias/acc_s); track max|qkv_f| ----
__global__ __launch_bounds__(256) void k_gemm_qkv(
    const signed char* __restrict__ A, const signed char* __restrict__ Bm,
    const float* __restrict__ swq, const float* __restrict__ bias,
    const unsigned* __restrict__ hdr, int* __restrict__ Cq, unsigned* __restrict__ gq) {
  __shared__ float red[4];
  int t = threadIdx.x;
  int lane = t & 63, w = t >> 6;
  int c = lane & 15, q = lane >> 4;
  int arow = blockIdx.y * 128 + (w & 1) * 64;
  int bcol = blockIdx.x * 128 + (w >> 1) * 64;
  i32x4 acc[4][4] = {};
  mfma_gemm_core(A, Bm, arow, bcol, c, q, acc);

  float s_x = fmaxf(__uint_as_float(hdr[0]) / 127.0f, EPSF);
  float lmax = 0.f;
#pragma unroll
  for (int j = 0; j < 4; ++j) {
    int ccol = bcol + j * 16 + c;
    float accs = s_x * swq[ccol];
    int bint = (int)rintf(bias[ccol] / accs);
#pragma unroll
    for (int i = 0; i < 4; ++i)
#pragma unroll
      for (int r = 0; r < 4; ++r) {
        int rr = arow + i * 16 + q * 4 + r;
        if (rr < M_ROWS) {
          int qv = acc[i][j][r] + bint;
          Cq[(size_t)rr * QKV_CH + ccol] = qv;
          lmax = fmaxf(lmax, fabsf((float)qv * accs));
        }
      }
  }
#pragma unroll
  for (int off = 32; off; off >>= 1) lmax = fmaxf(lmax, __shfl_xor(lmax, off, 64));
  if (lane == 0) red[w] = lmax;
  __syncthreads();
  if (t == 0)
    atomicMax(gq, __float_as_uint(fmaxf(fmaxf(red[0], red[1]), fmaxf(red[2], red[3]))));
}

// ---------------- per-channel fixedpoint requant constants for qkv ----------------
__global__ void k_qkv_prep(const float* __restrict__ swq, const unsigned* __restrict__ hdr,
                           float* __restrict__ mq, float* __restrict__ pwq) {
  int o = blockIdx.x * blockDim.x + threadIdx.x;
  if (o >= QKV_CH) return;
  float s_x = fmaxf(__uint_as_float(hdr[0]) / 127.0f, EPSF);
  float s_qkv = fmaxf(__uint_as_float(hdr[1]) / 127.0f, EPSF);
  float ns = (s_x * swq[o]) / s_qkv;
  int e;
  float f = frexpf(ns, &e);
  mq[o] = floorf(f * F2P31 + 0.5f);
  pwq[o] = exp2f((float)e - 31.0f);
}

// ---------------- requant qkv -> int8 (2D grid, no div/mod) ----------------
__global__ __launch_bounds__(256) void k_qkv_requant(
    const int* __restrict__ Cq, const float* __restrict__ swq,
    const float* __restrict__ mq, const float* __restrict__ pwq,
    const unsigned* __restrict__ hdr,
    signed char* __restrict__ Q8, signed char* __restrict__ K8,
    signed char* __restrict__ VT8) {
  float s_x = fmaxf(__uint_as_float(hdr[0]) / 127.0f, EPSF);
  int o = blockIdx.x * blockDim.x + threadIdx.x;   // [0, QKV_CH)
  int bn = blockIdx.y;                             // [0, M_ROWS)
  float accs = s_x * swq[o];
  float qf = (float)Cq[(size_t)bn * QKV_CH + o] * accs;
  float z = rintf(qf / accs);
  float t8 = rintf((z * mq[o]) * pwq[o]);
  t8 = fminf(fmaxf(t8, -128.f), 127.f);
  int s = o / CH;                                  // 0..2 (compile-time magic-mul)
  int rem = o - s * CH;
  int h = rem >> 6, d = rem & 63;
  int b = bn / SEQ, n = bn - b * SEQ;
  int bh = b * NH + h;
  signed char v = (signed char)t8;
  if (s == 0) Q8[(((size_t)bh * SEQ + n) << 6) + d] = v;
  else if (s == 1) K8[(((size_t)bh * SEQ + n) << 6) + d] = v;
  else VT8[(size_t)bh * (64 * VT_ROW) + (size_t)d * VT_ROW + n] = v;
}

// ---------------- attention: 1 wave per (bh, 16-query tile); two-pass, factor==1 fast path ----
__global__ __launch_bounds__(64, 4) void k_attn(
    const signed char* __restrict__ Q8, const signed char* __restrict__ K8,
    const signed char* __restrict__ VT8, const unsigned* __restrict__ hdr,
    int* __restrict__ ctxi, unsigned* __restrict__ gctx) {
  __shared__ unsigned char P[16 * P_STRIDE];   // probs [row][m]
  int t = threadIdx.x;
  int qt = blockIdx.x, bh = blockIdx.y;
  int b = bh / NH, h = bh - b * NH;
  int col = t & 15, q4 = t >> 4;

  // zero P pad region m in [576, 640) for every row
  for (int i = t; i < 16 * 16; i += 64) {
    int r = i >> 4, w = i & 15;
    *(int*)&P[r * P_STRIDE + 576 + (w << 2)] = 0;
  }
  __syncthreads();

  const signed char* Qb = Q8 + (((size_t)bh * SEQ + qt * 16 + col) << 6);
  long qa0 = *(const long*)(Qb + q4 * 8);
  long qa1 = *(const long*)(Qb + 32 + q4 * 8);
  const signed char* Kb = K8 + ((size_t)bh * SEQ << 6);

  // ---- pass A: row max only (logits discarded -> low VGPR) ----
  int mx[4] = {-2147483647 - 1, -2147483647 - 1, -2147483647 - 1, -2147483647 - 1};
  for (int kt = 0; kt < 37; ++kt) {
    const signed char* kr = Kb + ((size_t)(kt * 16 + col) << 6);
    long kb0 = *(const long*)(kr + q4 * 8);
    long kb1 = *(const long*)(kr + 32 + q4 * 8);
    i32x4 a = {0, 0, 0, 0};
    a = __builtin_amdgcn_mfma_i32_16x16x32_i8(qa0, kb0, a, 0, 0, 0);
    a = __builtin_amdgcn_mfma_i32_16x16x32_i8(qa1, kb1, a, 0, 0, 0);
    bool valid = (kt < 36) | (col < 1);
#pragma unroll
    for (int r = 0; r < 4; ++r)
      if (valid) mx[r] = max(mx[r], a[r]);
  }
#pragma unroll
  for (int r = 0; r < 4; ++r) {
    mx[r] = max(mx[r], __shfl_xor(mx[r], 1, 64));
    mx[r] = max(mx[r], __shfl_xor(mx[r], 2, 64));
    mx[r] = max(mx[r], __shfl_xor(mx[r], 4, 64));
    mx[r] = max(mx[r], __shfl_xor(mx[r], 8, 64));
  }

  float s_qkv = fmaxf(__uint_as_float(hdr[1]) / 127.0f, EPSF);
  float s_attn = (s_qkv * s_qkv) * 0.125f;
  float x0 = floorf(-1.0f / s_attn);
  float nx0 = 15.0f * x0;

  // ---- pass B: recompute logits, softmax, pack assuming factor==1 ----
  double dsum[4] = {0.0, 0.0, 0.0, 0.0};
  for (int kt = 0; kt < 37; ++kt) {
    const signed char* kr = Kb + ((size_t)(kt * 16 + col) << 6);
    long kb0 = *(const long*)(kr + q4 * 8);
    long kb1 = *(const long*)(kr + 32 + q4 * 8);
    i32x4 a = {0, 0, 0, 0};
    a = __builtin_amdgcn_mfma_i32_16x16x32_i8(qa0, kb0, a, 0, 0, 0);
    a = __builtin_amdgcn_mfma_i32_16x16x32_i8(qa1, kb1, a, 0, 0, 0);
    bool valid = (kt < 36) | (col < 1);
#pragma unroll
    for (int r = 0; r < 4; ++r) {
      float e = softmax_e(a[r], mx[r], x0, nx0);
      e = valid ? e : 0.0f;
      dsum[r] += (double)e;   // exact ints, order-free
      int p = (int)floorf(e * 5.9604644775390625e-08f);  // floor((e*1)/2^24)
      P[(q4 * 4 + r) * P_STRIDE + kt * 16 + col] = (unsigned char)p;
    }
  }
  float fac[4];
  bool bad = false;
#pragma unroll
  for (int r = 0; r < 4; ++r) {
    double d = dsum[r];
    d += __shfl_xor(d, 1, 64);
    d += __shfl_xor(d, 2, 64);
    d += __shfl_xor(d, 4, 64);
    d += __shfl_xor(d, 8, 64);
    float esum = fminf((float)d, F2P31);
    fac[r] = floorf(F2P31 / esum);
    bad |= (fac[r] != 1.0f);
  }
  if (__any(bad)) {
    // rare fallback: esum below clamp for some row -> redo pack with true factor
    for (int kt = 0; kt < 37; ++kt) {
      const signed char* kr = Kb + ((size_t)(kt * 16 + col) << 6);
      long kb0 = *(const long*)(kr + q4 * 8);
      long kb1 = *(const long*)(kr + 32 + q4 * 8);
      i32x4 a = {0, 0, 0, 0};
      a = __builtin_amdgcn_mfma_i32_16x16x32_i8(qa0, kb0, a, 0, 0, 0);
      a = __builtin_amdgcn_mfma_i32_16x16x32_i8(qa1, kb1, a, 0, 0, 0);
      bool valid = (kt < 36) | (col < 1);
#pragma unroll
      for (int r = 0; r < 4; ++r) {
        float e = softmax_e(a[r], mx[r], x0, nx0);
        e = valid ? e : 0.0f;
        int p = (int)floorf((e * fac[r]) * 5.9604644775390625e-08f);
        P[(q4 * 4 + r) * P_STRIDE + kt * 16 + col] = (unsigned char)p;
      }
    }
  }
  __syncthreads();

  // ---- PV: 20 m-chunks x 4 d-tiles ----
  const signed char* Vb = VT8 + (size_t)bh * (64 * VT_ROW);
  i32x4 acc2[4] = {{0,0,0,0}, {0,0,0,0}, {0,0,0,0}, {0,0,0,0}};
  for (int mc = 0; mc < 20; ++mc) {
    long pa = *(const long*)&P[col * P_STRIDE + mc * 32 + q4 * 8];
#pragma unroll
    for (int ct = 0; ct < 4; ++ct) {
      long vb = *(const long*)(Vb + (size_t)(ct * 16 + col) * VT_ROW + mc * 32 + q4 * 8);
      acc2[ct] = __builtin_amdgcn_mfma_i32_16x16x32_i8(pa, vb, acc2[ct], 0, 0, 0);
    }
  }

  float pre_s = 0.0078125f * s_qkv;
  float avmax = 0.f;
#pragma unroll
  for (int r = 0; r < 4; ++r) {
    int n = qt * 16 + q4 * 4 + r;
    if (n < SEQ) {
#pragma unroll
      for (int ct = 0; ct < 4; ++ct) {
        int cacc = acc2[ct][r];
        ctxi[((size_t)(b * SEQ + n)) * CH + h * 64 + ct * 16 + col] = cacc;
        avmax = fmaxf(avmax, fabsf((float)cacc * pre_s));
      }
    }
  }
#pragma unroll
  for (int off = 32; off; off >>= 1) avmax = fmaxf(avmax, __shfl_xor(avmax, off, 64));
  if (t == 0) atomicMax(gctx, __float_as_uint(avmax));
}

// ---------------- requant ctx -> int8 ----------------
__global__ void k_ctx_requant(const int* __restrict__ ctxi, const unsigned* __restrict__ hdr,
                              signed char* __restrict__ C8) {
  float s_qkv = fmaxf(__uint_as_float(hdr[1]) / 127.0f, EPSF);
  float pre_s = 0.0078125f * s_qkv;
  float s_ctx = fmaxf(__uint_as_float(hdr[2]) / 127.0f, EPSF);
  float ns = pre_s / s_ctx;
  int e;
  float f = frexpf(ns, &e);
  float mm = floorf(f * F2P31 + 0.5f);
  float pw = exp2f((float)e - 31.0f);
  int total = M_ROWS * CH;
  int stride = gridDim.x * blockDim.x;
  for (int i = blockIdx.x * blockDim.x + threadIdx.x; i < total; i += stride) {
    float cf = (float)ctxi[i] * pre_s;
    float z = rintf(cf / pre_s);
    float t8 = rintf((z * mm) * pw);
    t8 = fminf(fmaxf(t8, -128.f), 127.f);
    C8[i] = (signed char)t8;
  }
}

// ---------------- GEMM2 (MFMA): out = (C8*WP8^T + rint(b/out_s)) * out_s ----------------
__global__ __launch_bounds__(256) void k_gemm_out(
    const signed char* __restrict__ A, const signed char* __restrict__ Bm,
    const float* __restrict__ swp, const float* __restrict__ bias,
    const unsigned* __restrict__ hdr, float* __restrict__ outp) {
  int t = threadIdx.x;
  int lane = t & 63, w = t >> 6;
  int c = lane & 15, q = lane >> 4;
  int arow = blockIdx.y * 128 + (w & 1) * 64;
  int bcol = blockIdx.x * 128 + (w >> 1) * 64;
  i32x4 acc[4][4] = {};
  mfma_gemm_core(A, Bm, arow, bcol, c, q, acc);

  float s_ctx = fmaxf(__uint_as_float(hdr[2]) / 127.0f, EPSF);
#pragma unroll
  for (int j = 0; j < 4; ++j) {
    int ccol = bcol + j * 16 + c;
    float outs = s_ctx * swp[ccol];
    int bint = (int)rintf(bias[ccol] / outs);
#pragma unroll
    for (int i = 0; i < 4; ++i)
#pragma unroll
      for (int r = 0; r < 4; ++r) {
        int rr = arow + i * 16 + q * 4 + r;
        if (rr < M_ROWS)
          outp[(size_t)rr * CH + ccol] = (float)(acc[i][j][r] + bint) * outs;
      }
  }
}

extern "C" void kernel_launch(void* const* d_in, const int* in_sizes, int n_in,
                              void* d_out, int out_size, void* d_ws, size_t ws_size,
                              hipStream_t stream) {
  const float* x = (const float*)d_in[0];
  const float* w_qkv = (const float*)d_in[1];
  const float* b_qkv = (const float*)d_in[2];
  const float* w_proj = (const float*)d_in[3];
  const float* b_proj = (const float*)d_in[4];
  float* outp = (float*)d_out;

  // ---- workspace: bump allocator, 4 KB aligned ----
  char* ws = (char*)d_ws;
  size_t off = 0;
  auto alloc = [&](size_t sz) -> char* {
    char* p = ws + off;
    off = (off + sz + 4095) & ~(size_t)4095;
    return p;
  };
  unsigned* hdr = (unsigned*)alloc(256);   // [0]=max|x| [1]=max|qkv_f| [2]=max|ctx_f|
  float* SWQ = (float*)alloc(QKV_CH * 4);
  float* SWP = (float*)alloc(CH * 4);
  float* MQ  = (float*)alloc(QKV_CH * 4);
  float* PWQ = (float*)alloc(QKV_CH * 4);
  signed char* WQ8 = (signed char*)alloc((size_t)QKV_CH * CH);
  signed char* WP8 = (signed char*)alloc((size_t)CH * CH);
  // +128 rows padding: MFMA GEMM reads (but never writes) rows beyond M_ROWS
  signed char* X8  = (signed char*)alloc((size_t)(M_ROWS + 128) * CH);
  signed char* Q8  = (signed char*)alloc((size_t)M_ROWS * CH);
  signed char* K8  = (signed char*)alloc((size_t)M_ROWS * CH);
  signed char* VT8 = (signed char*)alloc((size_t)BQ * NH * 64 * VT_ROW);
  signed char* C8  = (signed char*)alloc((size_t)(M_ROWS + 128) * CH);
  int* QKVI = (int*)alloc((size_t)M_ROWS * QKV_CH * 4);
  int* CTXI = (int*)alloc((size_t)M_ROWS * CH * 4);
  (void)ws_size;

  hipMemsetAsync(hdr, 0, 256, stream);
  int nx = BQ * SEQ * CH;
  k_absmax<<<1024, 256, 0, stream>>>(x, nx, hdr + 0);
  k_wquant<<<QKV_CH, 256, 0, stream>>>(w_qkv, CH, WQ8, SWQ);
  k_wquant<<<CH, 256, 0, stream>>>(w_proj, CH, WP8, SWP);
  k_aquant<<<2048, 256, 0, stream>>>(x, nx, hdr, X8);
  dim3 g1(QKV_CH / 128, (M_ROWS + 127) / 128);
  k_gemm_qkv<<<g1, 256, 0, stream>>>(X8, WQ8, SWQ, b_qkv, hdr, QKVI, hdr + 1);
  k_qkv_prep<<<(QKV_CH + 255) / 256, 256, 0, stream>>>(SWQ, hdr, MQ, PWQ);
  dim3 gr(QKV_CH / 256, M_ROWS);
  k_qkv_requant<<<gr, 256, 0, stream>>>(QKVI, SWQ, MQ, PWQ, hdr, Q8, K8, VT8);
  dim3 ga(37, BQ * NH);
  k_attn<<<ga, 64, 0, stream>>>(Q8, K8, VT8, hdr, CTXI, hdr + 2);
  k_ctx_requant<<<2048, 256, 0, stream>>>(CTXI, hdr, C8);
  dim3 g2(CH / 128, (M_ROWS + 127) / 128);
  k_gemm_out<<<g2, 256, 0, stream>>>(C8, WP8, SWP, b_proj, hdr, outp);
}

// Round 7
// 256.798 us; speedup vs baseline: 3.7217x; 1.1443x over previous
//
#include <hip/hip_runtime.h>
#include <math.h>

// Problem constants
#define BQ 8
#define SEQ 577
#define CH 768
#define NH 12
#define HD 64
#define M_ROWS (BQ * SEQ)      // 4616
#define QKV_CH (3 * CH)        // 2304
#define EPSF 1.1920929e-07f
#define F2P31 2147483648.0f    // float32(2^31 - 1) rounds to 2^31 -- replicate jnp

#define VT_ROW 640             // Vt row bytes (577 padded, 64B-aligned rows)
#define P_STRIDE 664           // P LDS row stride bytes

typedef __attribute__((ext_vector_type(4))) int i32x4;
typedef struct __align__(16) { long x, y; } L2T;

#if defined(__has_builtin)
#  if __has_builtin(__builtin_amdgcn_sdot4)
#    define HAVE_SDOT4 1
#  endif
#endif

__device__ __forceinline__ int dot4(int a, int b, int c) {
#ifdef HAVE_SDOT4
  return __builtin_amdgcn_sdot4(a, b, c, false);
#else
  c += (int)(signed char)(a)       * (int)(signed char)(b);
  c += (int)(signed char)(a >> 8)  * (int)(signed char)(b >> 8);
  c += (int)(signed char)(a >> 16) * (int)(signed char)(b >> 16);
  c += (int)(signed char)(a >> 24) * (int)(signed char)(b >> 24);
  return c;
#endif
}

// shiftmax exp_int: bit-exact replication of reference f32 op sequence.
__device__ __forceinline__ float softmax_e(int svr, int mxr, float x0, float nx0) {
  float xi = (float)(svr - mxr);
  xi = xi + floorf(xi * 0.5f) - floorf(xi * 0.0625f);  // exact pow2 ops on ints
  xi = fmaxf(xi, nx0);
  float qd = floorf(xi / x0);                          // correctly-rounded fdiv, as ref
  float rr = xi - x0 * qd;
  int qi = (int)qd;                                    // in [0,15] for valid lanes
  float p2 = __int_as_float((142 - qi) << 23);         // 2^(15-qi) exact
  float e = floorf((rr * 0.5f - x0) * p2);
  return fmaxf(e, 0.0f);
}

// ---------------- global abs-max of a float tensor (exact, order-independent) --------
__global__ void k_absmax(const float* __restrict__ x, int n, unsigned* __restrict__ gmax) {
  float m = 0.f;
  int stride = gridDim.x * blockDim.x;
  for (int i = blockIdx.x * blockDim.x + threadIdx.x; i < n; i += stride)
    m = fmaxf(m, fabsf(x[i]));
#pragma unroll
  for (int off = 32; off; off >>= 1) m = fmaxf(m, __shfl_xor(m, off, 64));
  __shared__ float red[4];
  if ((threadIdx.x & 63) == 0) red[threadIdx.x >> 6] = m;
  __syncthreads();
  if (threadIdx.x == 0) {
    float mm = red[0];
    for (int i = 1; i < (int)(blockDim.x >> 6); ++i) mm = fmaxf(mm, red[i]);
    atomicMax(gmax, __float_as_uint(mm));
  }
}

// ---------------- per-row weight quant ----------------
__global__ void k_wquant(const float* __restrict__ w, int K,
                         signed char* __restrict__ w8, float* __restrict__ sw) {
  int row = blockIdx.x;
  const float* wr = w + (size_t)row * K;
  float m = 0.f;
  for (int c = threadIdx.x; c < K; c += blockDim.x) m = fmaxf(m, fabsf(wr[c]));
#pragma unroll
  for (int off = 32; off; off >>= 1) m = fmaxf(m, __shfl_xor(m, off, 64));
  __shared__ float red[4];
  if ((threadIdx.x & 63) == 0) red[threadIdx.x >> 6] = m;
  __syncthreads();
  float mm = fmaxf(fmaxf(red[0], red[1]), fmaxf(red[2], red[3]));
  float s = fmaxf(mm / 127.0f, EPSF);
  if (threadIdx.x == 0) sw[row] = s;
  for (int c = threadIdx.x; c < K; c += blockDim.x) {
    float q = rintf(wr[c] / s);
    q = fminf(fmaxf(q, -128.f), 127.f);
    w8[(size_t)row * K + c] = (signed char)q;
  }
}

// ---------------- per-tensor activation quant ----------------
__global__ void k_aquant(const float* __restrict__ x, int n,
                         const unsigned* __restrict__ hdr, signed char* __restrict__ x8) {
  float s = fmaxf(__uint_as_float(hdr[0]) / 127.0f, EPSF);
  int stride = gridDim.x * blockDim.x;
  for (int i = blockIdx.x * blockDim.x + threadIdx.x; i < n; i += stride) {
    float q = rintf(x[i] / s);
    q = fminf(fmaxf(q, -128.f), 127.f);
    x8[i] = (signed char)q;
  }
}

// ---- shared MFMA accumulate: 128x128 block tile, wave w does 64x64, frags from global ----
__device__ __forceinline__ void mfma_gemm_core(
    const signed char* __restrict__ A, const signed char* __restrict__ Bm,
    int arow, int bcol, int c, int q, i32x4 acc[4][4]) {
  for (int k0 = 0; k0 < CH; k0 += 64) {
    L2T af[4], bf[4];
#pragma unroll
    for (int i = 0; i < 4; ++i)
      af[i] = *(const L2T*)(A + (size_t)(arow + i * 16 + c) * CH + k0 + q * 16);
#pragma unroll
    for (int j = 0; j < 4; ++j)
      bf[j] = *(const L2T*)(Bm + (size_t)(bcol + j * 16 + c) * CH + k0 + q * 16);
#pragma unroll
    for (int i = 0; i < 4; ++i)
#pragma unroll
      for (int j = 0; j < 4; ++j) {
        acc[i][j] = __builtin_amdgcn_mfma_i32_16x16x32_i8(af[i].x, bf[j].x, acc[i][j], 0, 0, 0);
        acc[i][j] = __builtin_amdgcn_mfma_i32_16x16x32_i8(af[i].y, bf[j].y, acc[i][j], 0, 0, 0);
      }
  }
}

// ---------------- GEMM1 (MFMA): qkv_int = X8*WQ8^T + rint(bias/acc_s); track max|qkv_f| ----
__global__ __launch_bounds__(256) void k_gemm_qkv(
    const signed char* __restrict__ A, const signed char* __restrict__ Bm,
    const float* __restrict__ swq, const float* __restrict__ bias,
    const unsigned* __restrict__ hdr, int* __restrict__ Cq, unsigned* __restrict__ gq) {
  __shared__ float red[4];
  int t = threadIdx.x;
  int lane = t & 63, w = t >> 6;
  int c = lane & 15, q = lane >> 4;
  int arow = blockIdx.y * 128 + (w & 1) * 64;
  int bcol = blockIdx.x * 128 + (w >> 1) * 64;
  i32x4 acc[4][4] = {};
  mfma_gemm_core(A, Bm, arow, bcol, c, q, acc);

  float s_x = fmaxf(__uint_as_float(hdr[0]) / 127.0f, EPSF);
  float lmax = 0.f;
#pragma unroll
  for (int j = 0; j < 4; ++j) {
    int ccol = bcol + j * 16 + c;
    float accs = s_x * swq[ccol];
    int bint = (int)rintf(bias[ccol] / accs);
#pragma unroll
    for (int i = 0; i < 4; ++i)
#pragma unroll
      for (int r = 0; r < 4; ++r) {
        int rr = arow + i * 16 + q * 4 + r;
        if (rr < M_ROWS) {
          int qv = acc[i][j][r] + bint;
          Cq[(size_t)rr * QKV_CH + ccol] = qv;
          lmax = fmaxf(lmax, fabsf((float)qv * accs));
        }
      }
  }
#pragma unroll
  for (int off = 32; off; off >>= 1) lmax = fmaxf(lmax, __shfl_xor(lmax, off, 64));
  if (lane == 0) red[w] = lmax;
  __syncthreads();
  if (t == 0)
    atomicMax(gq, __float_as_uint(fmaxf(fmaxf(red[0], red[1]), fmaxf(red[2], red[3]))));
}

// ---------------- per-channel fixedpoint requant constants for qkv ----------------
__global__ void k_qkv_prep(const float* __restrict__ swq, const unsigned* __restrict__ hdr,
                           float* __restrict__ mq, float* __restrict__ pwq) {
  int o = blockIdx.x * blockDim.x + threadIdx.x;
  if (o >= QKV_CH) return;
  float s_x = fmaxf(__uint_as_float(hdr[0]) / 127.0f, EPSF);
  float s_qkv = fmaxf(__uint_as_float(hdr[1]) / 127.0f, EPSF);
  float ns = (s_x * swq[o]) / s_qkv;
  int e;
  float f = frexpf(ns, &e);
  mq[o] = floorf(f * F2P31 + 0.5f);
  pwq[o] = exp2f((float)e - 31.0f);
}

// ---------------- requant qkv -> int8 (2D grid, no div/mod) ----------------
__global__ __launch_bounds__(256) void k_qkv_requant(
    const int* __restrict__ Cq, const float* __restrict__ swq,
    const float* __restrict__ mq, const float* __restrict__ pwq,
    const unsigned* __restrict__ hdr,
    signed char* __restrict__ Q8, signed char* __restrict__ K8,
    signed char* __restrict__ VT8) {
  float s_x = fmaxf(__uint_as_float(hdr[0]) / 127.0f, EPSF);
  int o = blockIdx.x * blockDim.x + threadIdx.x;   // [0, QKV_CH)
  int bn = blockIdx.y;                             // [0, M_ROWS)
  float accs = s_x * swq[o];
  float qf = (float)Cq[(size_t)bn * QKV_CH + o] * accs;
  float z = rintf(qf / accs);
  float t8 = rintf((z * mq[o]) * pwq[o]);
  t8 = fminf(fmaxf(t8, -128.f), 127.f);
  int s = o / CH;
  int rem = o - s * CH;
  int h = rem >> 6, d = rem & 63;
  int b = bn / SEQ, n = bn - b * SEQ;
  int bh = b * NH + h;
  signed char v = (signed char)t8;
  if (s == 0) Q8[(((size_t)bh * SEQ + n) << 6) + d] = v;
  else if (s == 1) K8[(((size_t)bh * SEQ + n) << 6) + d] = v;
  else VT8[(size_t)bh * (64 * VT_ROW) + (size_t)d * VT_ROW + n] = v;
}

// ---- attention: 256-thr block per (qt, bh); 4 waves split 37 kv-tiles; single pass ----
__global__ __launch_bounds__(256, 4) void k_attn(
    const signed char* __restrict__ Q8, const signed char* __restrict__ K8,
    const signed char* __restrict__ VT8, const unsigned* __restrict__ hdr,
    int* __restrict__ ctxi, unsigned* __restrict__ gctx) {
  __shared__ unsigned char P[16 * P_STRIDE];   // probs [row][m]
  __shared__ int Rmax[4][16];                  // per-wave row maxima
  __shared__ double Rsum[4][16];               // per-wave row exp-sums (exact ints)
  __shared__ float Rav[4];
  int tid = threadIdx.x;
  int t = tid & 63, wid = tid >> 6;
  int qt = blockIdx.x, bh = blockIdx.y;
  int b = bh / NH, h = bh - b * NH;
  int col = t & 15, q4 = t >> 4;

  // zero P pad bytes m in [576,640) for all 16 rows (one int per thread)
  {
    int r = tid >> 4, w4 = tid & 15;
    *(int*)&P[r * P_STRIDE + 576 + (w4 << 2)] = 0;
  }

  const signed char* Qb = Q8 + (((size_t)bh * SEQ + qt * 16 + col) << 6);
  long qa0 = *(const long*)(Qb + q4 * 8);
  long qa1 = *(const long*)(Qb + 32 + q4 * 8);
  const signed char* Kb = K8 + ((size_t)bh * SEQ << 6);

  // kv-tile partition: wave0 -> 10 tiles, waves1-3 -> 9 each (total 37, disjoint)
  int kt0 = (wid == 0) ? 0 : 10 + (wid - 1) * 9;
  int ktn = (wid == 0) ? 10 : 9;

  // ---- QK^T once; logits in registers ----
  i32x4 sv[10];
  int mx[4] = {-2147483647 - 1, -2147483647 - 1, -2147483647 - 1, -2147483647 - 1};
#pragma unroll
  for (int u = 0; u < 10; ++u) {
    if (u < ktn) {
      int kt = kt0 + u;
      const signed char* kr = Kb + ((size_t)(kt * 16 + col) << 6);
      long kb0 = *(const long*)(kr + q4 * 8);
      long kb1 = *(const long*)(kr + 32 + q4 * 8);
      i32x4 a = {0, 0, 0, 0};
      a = __builtin_amdgcn_mfma_i32_16x16x32_i8(qa0, kb0, a, 0, 0, 0);
      a = __builtin_amdgcn_mfma_i32_16x16x32_i8(qa1, kb1, a, 0, 0, 0);
      sv[u] = a;
      bool valid = (kt < 36) | (col < 1);
#pragma unroll
      for (int r = 0; r < 4; ++r)
        if (valid) mx[r] = max(mx[r], a[r]);
    }
  }
#pragma unroll
  for (int r = 0; r < 4; ++r) {
    mx[r] = max(mx[r], __shfl_xor(mx[r], 1, 64));
    mx[r] = max(mx[r], __shfl_xor(mx[r], 2, 64));
    mx[r] = max(mx[r], __shfl_xor(mx[r], 4, 64));
    mx[r] = max(mx[r], __shfl_xor(mx[r], 8, 64));
  }
  if (col == 0) {
#pragma unroll
    for (int r = 0; r < 4; ++r) Rmax[wid][q4 * 4 + r] = mx[r];
  }
  __syncthreads();
#pragma unroll
  for (int r = 0; r < 4; ++r) {
    int row = q4 * 4 + r;
    mx[r] = max(max(Rmax[0][row], Rmax[1][row]), max(Rmax[2][row], Rmax[3][row]));
  }

  float s_qkv = fmaxf(__uint_as_float(hdr[1]) / 127.0f, EPSF);
  float s_attn = (s_qkv * s_qkv) * 0.125f;
  float x0 = floorf(-1.0f / s_attn);
  float nx0 = 15.0f * x0;

  // ---- softmax on stored logits; exp values kept in sv (as float bits) ----
  double ds[4] = {0.0, 0.0, 0.0, 0.0};
#pragma unroll
  for (int u = 0; u < 10; ++u) {
    if (u < ktn) {
      int kt = kt0 + u;
      bool valid = (kt < 36) | (col < 1);
#pragma unroll
      for (int r = 0; r < 4; ++r) {
        float e = softmax_e(sv[u][r], mx[r], x0, nx0);
        e = valid ? e : 0.0f;
        ds[r] += (double)e;   // exact integer values -> order-free
        sv[u][r] = __float_as_int(e);
      }
    }
  }
#pragma unroll
  for (int r = 0; r < 4; ++r) {
    ds[r] += __shfl_xor(ds[r], 1, 64);
    ds[r] += __shfl_xor(ds[r], 2, 64);
    ds[r] += __shfl_xor(ds[r], 4, 64);
    ds[r] += __shfl_xor(ds[r], 8, 64);
  }
  if (col == 0) {
#pragma unroll
    for (int r = 0; r < 4; ++r) Rsum[wid][q4 * 4 + r] = ds[r];
  }
  __syncthreads();
  float fac[4];
#pragma unroll
  for (int r = 0; r < 4; ++r) {
    int row = q4 * 4 + r;
    double d = ((Rsum[0][row] + Rsum[1][row]) + Rsum[2][row]) + Rsum[3][row];
    float esum = fminf((float)d, F2P31);
    fac[r] = floorf(F2P31 / esum);
  }

  // ---- pack probs to LDS [row][m] bytes ----
#pragma unroll
  for (int u = 0; u < 10; ++u) {
    if (u < ktn) {
      int kt = kt0 + u;
#pragma unroll
      for (int r = 0; r < 4; ++r) {
        float e = __int_as_float(sv[u][r]);
        int p = (int)floorf((e * fac[r]) * 5.9604644775390625e-08f);  // /2^24 exact
        P[(q4 * 4 + r) * P_STRIDE + kt * 16 + col] = (unsigned char)p;
      }
    }
  }
  __syncthreads();

  // ---- PV: wave wid handles d-tile ct=wid; 20 m-chunks ----
  const signed char* Vb = VT8 + (size_t)bh * (64 * VT_ROW);
  i32x4 acc = {0, 0, 0, 0};
  for (int mc = 0; mc < 20; ++mc) {
    long pa = *(const long*)&P[col * P_STRIDE + mc * 32 + q4 * 8];
    long vb = *(const long*)(Vb + (size_t)(wid * 16 + col) * VT_ROW + mc * 32 + q4 * 8);
    acc = __builtin_amdgcn_mfma_i32_16x16x32_i8(pa, vb, acc, 0, 0, 0);
  }

  float pre_s = 0.0078125f * s_qkv;
  float avmax = 0.f;
#pragma unroll
  for (int r = 0; r < 4; ++r) {
    int n = qt * 16 + q4 * 4 + r;
    if (n < SEQ) {
      int cacc = acc[r];
      ctxi[((size_t)(b * SEQ + n)) * CH + h * 64 + wid * 16 + col] = cacc;
      avmax = fmaxf(avmax, fabsf((float)cacc * pre_s));
    }
  }
#pragma unroll
  for (int off = 32; off; off >>= 1) avmax = fmaxf(avmax, __shfl_xor(avmax, off, 64));
  if (t == 0) Rav[wid] = avmax;
  __syncthreads();
  if (tid == 0)
    atomicMax(gctx, __float_as_uint(fmaxf(fmaxf(Rav[0], Rav[1]), fmaxf(Rav[2], Rav[3]))));
}

// ---------------- requant ctx -> int8 ----------------
__global__ void k_ctx_requant(const int* __restrict__ ctxi, const unsigned* __restrict__ hdr,
                              signed char* __restrict__ C8) {
  float s_qkv = fmaxf(__uint_as_float(hdr[1]) / 127.0f, EPSF);
  float pre_s = 0.0078125f * s_qkv;
  float s_ctx = fmaxf(__uint_as_float(hdr[2]) / 127.0f, EPSF);
  float ns = pre_s / s_ctx;
  int e;
  float f = frexpf(ns, &e);
  float mm = floorf(f * F2P31 + 0.5f);
  float pw = exp2f((float)e - 31.0f);
  int total = M_ROWS * CH;
  int stride = gridDim.x * blockDim.x;
  for (int i = blockIdx.x * blockDim.x + threadIdx.x; i < total; i += stride) {
    float cf = (float)ctxi[i] * pre_s;
    float z = rintf(cf / pre_s);
    float t8 = rintf((z * mm) * pw);
    t8 = fminf(fmaxf(t8, -128.f), 127.f);
    C8[i] = (signed char)t8;
  }
}

// ---------------- GEMM2 (MFMA): out = (C8*WP8^T + rint(b/out_s)) * out_s ----------------
__global__ __launch_bounds__(256) void k_gemm_out(
    const signed char* __restrict__ A, const signed char* __restrict__ Bm,
    const float* __restrict__ swp, const float* __restrict__ bias,
    const unsigned* __restrict__ hdr, float* __restrict__ outp) {
  int t = threadIdx.x;
  int lane = t & 63, w = t >> 6;
  int c = lane & 15, q = lane >> 4;
  int arow = blockIdx.y * 128 + (w & 1) * 64;
  int bcol = blockIdx.x * 128 + (w >> 1) * 64;
  i32x4 acc[4][4] = {};
  mfma_gemm_core(A, Bm, arow, bcol, c, q, acc);

  float s_ctx = fmaxf(__uint_as_float(hdr[2]) / 127.0f, EPSF);
#pragma unroll
  for (int j = 0; j < 4; ++j) {
    int ccol = bcol + j * 16 + c;
    float outs = s_ctx * swp[ccol];
    int bint = (int)rintf(bias[ccol] / outs);
#pragma unroll
    for (int i = 0; i < 4; ++i)
#pragma unroll
      for (int r = 0; r < 4; ++r) {
        int rr = arow + i * 16 + q * 4 + r;
        if (rr < M_ROWS)
          outp[(size_t)rr * CH + ccol] = (float)(acc[i][j][r] + bint) * outs;
      }
  }
}

extern "C" void kernel_launch(void* const* d_in, const int* in_sizes, int n_in,
                              void* d_out, int out_size, void* d_ws, size_t ws_size,
                              hipStream_t stream) {
  const float* x = (const float*)d_in[0];
  const float* w_qkv = (const float*)d_in[1];
  const float* b_qkv = (const float*)d_in[2];
  const float* w_proj = (const float*)d_in[3];
  const float* b_proj = (const float*)d_in[4];
  float* outp = (float*)d_out;

  // ---- workspace: bump allocator, 4 KB aligned ----
  char* ws = (char*)d_ws;
  size_t off = 0;
  auto alloc = [&](size_t sz) -> char* {
    char* p = ws + off;
    off = (off + sz + 4095) & ~(size_t)4095;
    return p;
  };
  unsigned* hdr = (unsigned*)alloc(256);   // [0]=max|x| [1]=max|qkv_f| [2]=max|ctx_f|
  float* SWQ = (float*)alloc(QKV_CH * 4);
  float* SWP = (float*)alloc(CH * 4);
  float* MQ  = (float*)alloc(QKV_CH * 4);
  float* PWQ = (float*)alloc(QKV_CH * 4);
  signed char* WQ8 = (signed char*)alloc((size_t)QKV_CH * CH);
  signed char* WP8 = (signed char*)alloc((size_t)CH * CH);
  // +128 rows padding: MFMA GEMM reads (but never writes) rows beyond M_ROWS
  signed char* X8  = (signed char*)alloc((size_t)(M_ROWS + 128) * CH);
  signed char* Q8  = (signed char*)alloc((size_t)M_ROWS * CH);
  signed char* K8  = (signed char*)alloc((size_t)M_ROWS * CH);
  signed char* VT8 = (signed char*)alloc((size_t)BQ * NH * 64 * VT_ROW);
  signed char* C8  = (signed char*)alloc((size_t)(M_ROWS + 128) * CH);
  int* QKVI = (int*)alloc((size_t)M_ROWS * QKV_CH * 4);
  int* CTXI = (int*)alloc((size_t)M_ROWS * CH * 4);
  (void)ws_size;

  hipMemsetAsync(hdr, 0, 256, stream);
  int nx = BQ * SEQ * CH;
  k_absmax<<<1024, 256, 0, stream>>>(x, nx, hdr + 0);
  k_wquant<<<QKV_CH, 256, 0, stream>>>(w_qkv, CH, WQ8, SWQ);
  k_wquant<<<CH, 256, 0, stream>>>(w_proj, CH, WP8, SWP);
  k_aquant<<<2048, 256, 0, stream>>>(x, nx, hdr, X8);
  dim3 g1(QKV_CH / 128, (M_ROWS + 127) / 128);
  k_gemm_qkv<<<g1, 256, 0, stream>>>(X8, WQ8, SWQ, b_qkv, hdr, QKVI, hdr + 1);
  k_qkv_prep<<<(QKV_CH + 255) / 256, 256, 0, stream>>>(SWQ, hdr, MQ, PWQ);
  dim3 gr(QKV_CH / 256, M_ROWS);
  k_qkv_requant<<<gr, 256, 0, stream>>>(QKVI, SWQ, MQ, PWQ, hdr, Q8, K8, VT8);
  dim3 ga(37, BQ * NH);
  k_attn<<<ga, 256, 0, stream>>>(Q8, K8, VT8, hdr, CTXI, hdr + 2);
  k_ctx_requant<<<2048, 256, 0, stream>>>(CTXI, hdr, C8);
  dim3 g2(CH / 128, (M_ROWS + 127) / 128);
  k_gemm_out<<<g2, 256, 0, stream>>>(C8, WP8, SWP, b_proj, hdr, outp);
}